// Round 10
// baseline (466.023 us; speedup 1.0000x reference)
//
#include <hip/hip_runtime.h>
#include <hip/hip_bf16.h>
#include <hip/hip_fp16.h>

typedef __hip_bfloat16 bf16;
typedef unsigned short ushort_t;
typedef __attribute__((ext_vector_type(8))) short bf16x8;
typedef __attribute__((ext_vector_type(16))) float f32x16;

__device__ __forceinline__ float us2f(unsigned short u) {
    unsigned int x = ((unsigned int)u) << 16;
    return __uint_as_float(x);
}
__device__ __forceinline__ ushort_t f2us(float f) {
    return ((__hip_bfloat16_raw)__float2bfloat16(f)).x;
}

// async global->LDS, 16 B per lane. LDS dest = wave-uniform base + lane*16.
__device__ __forceinline__ void gl_lds16(const ushort_t* g, ushort_t* l) {
    __builtin_amdgcn_global_load_lds(
        (const __attribute__((address_space(1))) void*)g,
        (__attribute__((address_space(3))) void*)l, 16, 0, 0);
}

// ---------------------------------------------------------------------------
// Fused input cast (float4): src_b = bf16(src), q_b = bf16(src + pos)
// ---------------------------------------------------------------------------
__global__ __launch_bounds__(256) void cast2_kernel(
    const float* __restrict__ src, const float* __restrict__ pos,
    bf16* __restrict__ src_b, bf16* __restrict__ q_b, int n)
{
    int i = (blockIdx.x * 256 + threadIdx.x) * 4;
    if (i < n) {
        const float4 s4 = *reinterpret_cast<const float4*>(&src[i]);
        const float4 p4 = *reinterpret_cast<const float4*>(&pos[i]);
        int2 sp, qp;
        sp.x = (unsigned)f2us(s4.x) | ((unsigned)f2us(s4.y) << 16);
        sp.y = (unsigned)f2us(s4.z) | ((unsigned)f2us(s4.w) << 16);
        qp.x = (unsigned)f2us(s4.x + p4.x) | ((unsigned)f2us(s4.y + p4.y) << 16);
        qp.y = (unsigned)f2us(s4.z + p4.z) | ((unsigned)f2us(s4.w + p4.w) << 16);
        *reinterpret_cast<int2*>((ushort_t*)src_b + i) = sp;
        *reinterpret_cast<int2*>((ushort_t*)q_b + i) = qp;
    }
}

// ---------------------------------------------------------------------------
// Fused weight prep. Small weights: transpose-cast to [N][K] bf16.
// w1/w2: packed FRAGMENT-MAJOR (unchanged from R9):
//   w1p (hcg,t,kw,lane): 16 B = w1[k=t*32+kw*16+(l>>5)*8+e][n=hcg*32+(l&31)]
//   w2p (c,nq,t,kw,lane): w2[f=c*128+t*32+kw*16+(l>>5)*8+e][n=nq*32+(l&31)]
// ---------------------------------------------------------------------------
__global__ __launch_bounds__(256) void prep_kernel(
    const float* __restrict__ wv, const float* __restrict__ wo,
    const float* __restrict__ wa, const float* __restrict__ wout,
    const float* __restrict__ w1, const float* __restrict__ w2,
    const float* __restrict__ bo, const float* __restrict__ ba,
    bf16* __restrict__ wvt, bf16* __restrict__ wcat, bf16* __restrict__ woutt,
    ushort_t* __restrict__ w1p, ushort_t* __restrict__ w2p,
    float* __restrict__ bcat)
{
    __shared__ float tile[32][33];
    const int b = blockIdx.x;
    const float* W; bf16* Wt = nullptr; ushort_t* Wp = nullptr;
    int K, N, tb, mode = 0;
    if (b < 64)        { W = wv;   Wt = wvt;            K = 256;  N = 256;  tb = b; }
    else if (b < 144)  { W = wo;   Wt = wcat;           K = 256;  N = 320;  tb = b - 64; }
    else if (b < 184)  { W = wa;   Wt = wcat + 320*256; K = 256;  N = 160;  tb = b - 144; }
    else if (b < 248)  { W = wout; Wt = woutt;          K = 256;  N = 256;  tb = b - 184; }
    else if (b < 760)  { W = w1;   Wp = w1p; mode = 1;  K = 256;  N = 2048; tb = b - 248; }
    else if (b < 1272) { W = w2;   Wp = w2p; mode = 2;  K = 2048; N = 256;  tb = b - 760; }
    else {
        int i = (b - 1272) * 256 + threadIdx.x;
        if (i < 320) bcat[i] = bo[i];
        else if (i < 480) bcat[i] = ba[i - 320];
        return;
    }
    const int ntn = N >> 5;
    const int nb = (tb % ntn) * 32, kb = (tb / ntn) * 32;
    const int tx = threadIdx.x & 31, ty = threadIdx.x >> 5;  // 32 x 8
    #pragma unroll
    for (int i = 0; i < 32; i += 8) {
        int k = kb + ty + i, n = nb + tx;
        tile[ty + i][tx] = (k < K && n < N) ? W[(size_t)k * N + n] : 0.f;
    }
    __syncthreads();
    if (mode == 0) {
        #pragma unroll
        for (int i = 0; i < 32; i += 8) {
            int n = nb + ty + i, k = kb + tx;
            if (n < N && k < K)
                Wt[(size_t)n * K + k] = __float2bfloat16(tile[tx][ty + i]);
        }
    } else if (threadIdx.x < 128) {
        const int l = threadIdx.x & 63, kw = threadIdx.x >> 6;
        const int kb8 = kw * 16 + (l >> 5) * 8;
        const int nx = l & 31;
        ushort_t tmp[8];
        #pragma unroll
        for (int e = 0; e < 8; ++e) tmp[e] = f2us(tile[kb8 + e][nx]);
        size_t base;
        if (mode == 1)
            base = ((size_t)(((nb >> 5) * 8 + (kb >> 5)) * 2 + kw)) * 512;
        else
            base = ((size_t)((((kb >> 7) * 8 + (nb >> 5)) * 4 + ((kb >> 5) & 3)) * 2 + kw)) * 512;
        *reinterpret_cast<int4*>(Wp + base + l * 8) =
            *reinterpret_cast<const int4*>(tmp);
    }
}

// ---------------------------------------------------------------------------
// MFMA bf16 GEMM (64x128 tile, M-split), swizzled-LDS, double-buffered.
// (proven R5/R6 kernel — used for the N=256,K=256 GEMMs: value, wout)
// ---------------------------------------------------------------------------
template<bool RELU, bool OUT_BF16, bool HAS_RESID, bool RESID_BF16, int NT, int WPE>
__global__ __launch_bounds__(256, WPE) void gemm_mfma_s(
    const ushort_t* __restrict__ A,    // [M][K] bf16
    const ushort_t* __restrict__ Bt,   // [N][K] bf16
    const float* __restrict__ bias,    // [N] f32
    const void* __restrict__ residv,   // [M][N] f32 or bf16
    void* __restrict__ outv, int M, int N, int K, int mtiles)
{
    __shared__ __align__(16) char smemraw[24576];
    ushort_t* Asmem = (ushort_t*)smemraw;
    ushort_t* Bsmem = (ushort_t*)(smemraw + 4096);
    float (*epi)[68] = (float(*)[68])smemraw;

    const int lid = blockIdx.x;
    const int tbk = lid >> 3;
    const int xb = tbk & (NT - 1);
    const int yg = (tbk / NT) * 8 + (lid & 7);
    if (yg >= mtiles) return;
    const int m0 = yg * 64;
    const int n0 = xb * 128;

    const int tid = threadIdx.x;
    const int lane = tid & 63;
    const int wave = tid >> 6;
    const int l32 = lane & 31;
    const int hi  = lane >> 5;
    const int wm = wave >> 1;
    const int wn = wave & 1;

    const int lsup = lane >> 3;
    const int clin = lane & 7;

    const int gsA = wave * 8 + lsup;
    const int csA = clin ^ (gsA & 7);
    int rA = m0 + gsA * 2 + (csA >> 2); if (rA > M - 1) rA = M - 1;
    const ushort_t* aP = A + (size_t)rA * K + (csA & 3) * 8;
    ushort_t* aL = Asmem + wave * 512;

    const ushort_t* bP[2]; ushort_t* bL[2];
    #pragma unroll
    for (int i = 0; i < 2; ++i) {
        const int gsB = wave * 16 + i * 8 + lsup;
        const int csB = clin ^ (gsB & 7);
        int rB = n0 + gsB * 2 + (csB >> 2); if (rB > N - 1) rB = N - 1;
        bP[i] = Bt + (size_t)rB * K + (csB & 3) * 8;
        bL[i] = Bsmem + (wave * 16 + i * 8) * 64;
    }

    const int arow = wm * 32 + l32;
    const int asup = arow >> 1;
    const ushort_t* aR[2];
    #pragma unroll
    for (int kw = 0; kw < 2; ++kw) {
        const int q = kw * 2 + hi;
        const int slot = (((arow & 1) << 2) | q) ^ (asup & 7);
        aR[kw] = Asmem + asup * 64 + slot * 8;
    }
    const ushort_t* bR[2][2];
    #pragma unroll
    for (int j = 0; j < 2; ++j) {
        const int brow = wn * 64 + j * 32 + l32;
        const int bsup = brow >> 1;
        #pragma unroll
        for (int kw = 0; kw < 2; ++kw) {
            const int q = kw * 2 + hi;
            const int slot = (((brow & 1) << 2) | q) ^ (bsup & 7);
            bR[j][kw] = Bsmem + bsup * 64 + slot * 8;
        }
    }

    f32x16 acc[2] = {};

    auto stage = [&](int ofs) {
        gl_lds16(aP, aL + ofs);             aP    += 32;
        gl_lds16(bP[0], bL[0] + ofs);       bP[0] += 32;
        gl_lds16(bP[1], bL[1] + ofs);       bP[1] += 32;
    };
    auto compute = [&](int ofs) {
        #pragma unroll
        for (int kw = 0; kw < 2; ++kw) {
            const bf16x8 af = *reinterpret_cast<const bf16x8*>(aR[kw] + ofs);
            #pragma unroll
            for (int j = 0; j < 2; ++j)
                acc[j] = __builtin_amdgcn_mfma_f32_32x32x16_bf16(
                    af, *reinterpret_cast<const bf16x8*>(bR[j][kw] + ofs),
                    acc[j], 0, 0, 0);
        }
    };

    const int ntile = K >> 5;
    stage(0);
    for (int t = 0; t < ntile; t += 2) {
        __syncthreads();
        stage(6144);
        compute(0);
        __syncthreads();
        if (t + 2 < ntile) stage(0);
        compute(6144);
    }
    __syncthreads();

    #pragma unroll
    for (int half = 0; half < 2; ++half) {
        if (wn == half) {
            #pragma unroll
            for (int j = 0; j < 2; ++j) {
                const int coll = j * 32 + l32;
                const int n = n0 + half * 64 + coll;
                const float bv = (n < N) ? bias[n] : 0.f;
                #pragma unroll
                for (int r = 0; r < 16; ++r) {
                    const int row = wm * 32 + hi * 4 + (r & 3) + (r >> 2) * 8;
                    epi[row][coll] = acc[j][r] + bv;
                }
            }
        }
        __syncthreads();
        #pragma unroll
        for (int i = 0; i < 4; ++i) {
            const int idx = i * 256 + tid;
            const int row = idx >> 4;
            const int c4  = idx & 15;
            const int m = m0 + row;
            const int n = n0 + half * 64 + c4 * 4;
            if (m < M && n + 3 < N) {
                float4 v = *reinterpret_cast<const float4*>(&epi[row][c4 * 4]);
                if (HAS_RESID) {
                    if (RESID_BF16) {
                        const int2 rw = *reinterpret_cast<const int2*>(
                            (const ushort_t*)residv + (size_t)m * N + n);
                        v.x += us2f((ushort_t)((unsigned)rw.x & 0xffffu));
                        v.y += us2f((ushort_t)((unsigned)rw.x >> 16));
                        v.z += us2f((ushort_t)((unsigned)rw.y & 0xffffu));
                        v.w += us2f((ushort_t)((unsigned)rw.y >> 16));
                    } else {
                        const float4 r4 = *reinterpret_cast<const float4*>(
                            (const float*)residv + (size_t)m * N + n);
                        v.x += r4.x; v.y += r4.y; v.z += r4.z; v.w += r4.w;
                    }
                }
                if (RELU) {
                    v.x = fmaxf(v.x, 0.f); v.y = fmaxf(v.y, 0.f);
                    v.z = fmaxf(v.z, 0.f); v.w = fmaxf(v.w, 0.f);
                }
                if (OUT_BF16) {
                    int2 pk;
                    pk.x = (unsigned)f2us(v.x) | ((unsigned)f2us(v.y) << 16);
                    pk.y = (unsigned)f2us(v.z) | ((unsigned)f2us(v.w) << 16);
                    *reinterpret_cast<int2*>((ushort_t*)outv + (size_t)m * N + n) = pk;
                } else {
                    *reinterpret_cast<float4*>((float*)outv + (size_t)m * N + n) = v;
                }
            }
        }
        if (half == 0) __syncthreads();
    }
}

// ---------------------------------------------------------------------------
// BIG MFMA bf16 GEMM: 128x128 tile (proven R7 kernel — used for og, N=480).
// ---------------------------------------------------------------------------
template<bool RELU, bool OUT_BF16, bool HAS_RESID, bool RESID_BF16, int NT>
__global__ __launch_bounds__(256, 4) void gemm_mfma_b(
    const ushort_t* __restrict__ A,    // [M][K] bf16
    const ushort_t* __restrict__ Bt,   // [N][K] bf16
    const float* __restrict__ bias,    // [N] f32
    const void* __restrict__ residv,   // [M][N] f32 or bf16
    void* __restrict__ outv, int M, int N, int K, int mtiles)
{
    __shared__ __align__(16) char smemraw[32768];
    ushort_t* Asmem = (ushort_t*)smemraw;
    ushort_t* Bsmem = (ushort_t*)(smemraw + 8192);
    float (*epi)[68] = (float(*)[68])smemraw;

    const int lid = blockIdx.x;
    const int tbk = lid >> 3;
    const int xb = tbk & (NT - 1);
    const int yg = (tbk / NT) * 8 + (lid & 7);
    if (yg >= mtiles) return;
    const int m0 = yg * 128;
    const int n0 = xb * 128;

    const int tid = threadIdx.x;
    const int lane = tid & 63;
    const int wave = tid >> 6;
    const int l32 = lane & 31;
    const int hi  = lane >> 5;
    const int wm = wave >> 1;
    const int wn = wave & 1;

    const int lsup = lane >> 3;
    const int clin = lane & 7;
    const ushort_t *aP[2], *bP[2];
    ushort_t *aL[2], *bL[2];
    #pragma unroll
    for (int i = 0; i < 2; ++i) {
        const int gs = wave * 16 + i * 8 + lsup;
        const int cs = clin ^ (gs & 7);
        int rA = m0 + gs * 2 + (cs >> 2); if (rA > M - 1) rA = M - 1;
        aP[i] = A + (size_t)rA * K + (cs & 3) * 8;
        aL[i] = Asmem + (wave * 16 + i * 8) * 64;
        int rB = n0 + gs * 2 + (cs >> 2); if (rB > N - 1) rB = N - 1;
        bP[i] = Bt + (size_t)rB * K + (cs & 3) * 8;
        bL[i] = Bsmem + (wave * 16 + i * 8) * 64;
    }

    const ushort_t* aR[2][2];
    const ushort_t* bR[2][2];
    #pragma unroll
    for (int mi = 0; mi < 2; ++mi) {
        const int arow = wm * 64 + mi * 32 + l32;
        const int asup = arow >> 1;
        #pragma unroll
        for (int kw = 0; kw < 2; ++kw) {
            const int q = kw * 2 + hi;
            const int slot = (((arow & 1) << 2) | q) ^ (asup & 7);
            aR[mi][kw] = Asmem + asup * 64 + slot * 8;
        }
    }
    #pragma unroll
    for (int ni = 0; ni < 2; ++ni) {
        const int brow = wn * 64 + ni * 32 + l32;
        const int bsup = brow >> 1;
        #pragma unroll
        for (int kw = 0; kw < 2; ++kw) {
            const int q = kw * 2 + hi;
            const int slot = (((brow & 1) << 2) | q) ^ (bsup & 7);
            bR[ni][kw] = Bsmem + bsup * 64 + slot * 8;
        }
    }

    f32x16 a00 = {}, a01 = {}, a10 = {}, a11 = {};

    auto stage = [&](int ofs) {
        gl_lds16(aP[0], aL[0] + ofs); aP[0] += 32;
        gl_lds16(aP[1], aL[1] + ofs); aP[1] += 32;
        gl_lds16(bP[0], bL[0] + ofs); bP[0] += 32;
        gl_lds16(bP[1], bL[1] + ofs); bP[1] += 32;
    };
    auto compute = [&](int ofs) {
        #pragma unroll
        for (int kw = 0; kw < 2; ++kw) {
            const bf16x8 af0 = *reinterpret_cast<const bf16x8*>(aR[0][kw] + ofs);
            const bf16x8 af1 = *reinterpret_cast<const bf16x8*>(aR[1][kw] + ofs);
            const bf16x8 bf0 = *reinterpret_cast<const bf16x8*>(bR[0][kw] + ofs);
            const bf16x8 bf1 = *reinterpret_cast<const bf16x8*>(bR[1][kw] + ofs);
            a00 = __builtin_amdgcn_mfma_f32_32x32x16_bf16(af0, bf0, a00, 0, 0, 0);
            a01 = __builtin_amdgcn_mfma_f32_32x32x16_bf16(af0, bf1, a01, 0, 0, 0);
            a10 = __builtin_amdgcn_mfma_f32_32x32x16_bf16(af1, bf0, a10, 0, 0, 0);
            a11 = __builtin_amdgcn_mfma_f32_32x32x16_bf16(af1, bf1, a11, 0, 0, 0);
        }
    };

    const int ntile = K >> 5;
    stage(0);
    for (int t = 0; t < ntile; t += 2) {
        __syncthreads();
        stage(8192);
        compute(0);
        __syncthreads();
        if (t + 2 < ntile) stage(0);
        compute(8192);
    }
    __syncthreads();

    #pragma unroll
    for (int qd = 0; qd < 4; ++qd) {
        const int rh = qd >> 1, ch = qd & 1;
        if (qd) __syncthreads();
        if (wm == rh && wn == ch) {
            #pragma unroll
            for (int ni = 0; ni < 2; ++ni) {
                const int col = ni * 32 + l32;
                const int n = n0 + ch * 64 + col;
                const float bv = (n < N) ? bias[n] : 0.f;
                #pragma unroll
                for (int mi = 0; mi < 2; ++mi) {
                    const f32x16& ac = (mi == 0) ? (ni == 0 ? a00 : a01)
                                                 : (ni == 0 ? a10 : a11);
                    #pragma unroll
                    for (int r = 0; r < 16; ++r) {
                        const int row = mi * 32 + hi * 4 + (r & 3) + (r >> 2) * 8;
                        epi[row][col] = ac[r] + bv;
                    }
                }
            }
        }
        __syncthreads();
        #pragma unroll
        for (int i = 0; i < 4; ++i) {
            const int idx = i * 256 + tid;
            const int row = idx >> 4;
            const int c4  = idx & 15;
            const int m = m0 + rh * 64 + row;
            const int n = n0 + ch * 64 + c4 * 4;
            if (m < M && n + 3 < N) {
                float4 v = *reinterpret_cast<const float4*>(&epi[row][c4 * 4]);
                if (HAS_RESID) {
                    if (RESID_BF16) {
                        const int2 rw = *reinterpret_cast<const int2*>(
                            (const ushort_t*)residv + (size_t)m * N + n);
                        v.x += us2f((ushort_t)((unsigned)rw.x & 0xffffu));
                        v.y += us2f((ushort_t)((unsigned)rw.x >> 16));
                        v.z += us2f((ushort_t)((unsigned)rw.y & 0xffffu));
                        v.w += us2f((ushort_t)((unsigned)rw.y >> 16));
                    } else {
                        const float4 r4 = *reinterpret_cast<const float4*>(
                            (const float*)residv + (size_t)m * N + n);
                        v.x += r4.x; v.y += r4.y; v.z += r4.z; v.w += r4.w;
                    }
                }
                if (RELU) {
                    v.x = fmaxf(v.x, 0.f); v.y = fmaxf(v.y, 0.f);
                    v.z = fmaxf(v.z, 0.f); v.w = fmaxf(v.w, 0.f);
                }
                if (OUT_BF16) {
                    int2 pk;
                    pk.x = (unsigned)f2us(v.x) | ((unsigned)f2us(v.y) << 16);
                    pk.y = (unsigned)f2us(v.z) | ((unsigned)f2us(v.w) << 16);
                    *reinterpret_cast<int2*>((ushort_t*)outv + (size_t)m * N + n) = pk;
                } else {
                    *reinterpret_cast<float4*>((float*)outv + (size_t)m * N + n) = v;
                }
            }
        }
    }
}

// ---------------------------------------------------------------------------
// FUSED FFN v3: out = LN2( x + relu(x@w1+b1)@w2 + b2 ).  h stays in REGISTERS.
// Stage 1 computes hT = mfma(A=w1-frag, B=x-frag) so each lane holds h for
// m = lane-local column; bias+relu+bf16-pack (8 u32) + __shfl_xor(·,32) to
// exchange hi/lo halves + 8 selects assemble the stage-2 A-fragments fully
// in registers. Each wave accumulates a PARTIAL z over all 256 cols for its
// own f-slice (za[8] f32x16, statically indexed) -> ZERO barriers and ZERO
// LDS traffic in the main loop. Cross-wave f-reduction: 4 staggered rounds
// through epi[32][260] (za index kept compile-time via guarded unrolls).
// Then +b2 +x-resid + LN2, f32 out. LDS 33280 B; ~215 VGPR -> (256,2).
// ---------------------------------------------------------------------------
__global__ __launch_bounds__(256, 2) void ffn_fused3(
    const ushort_t* __restrict__ X,    // [M][256] bf16 (post-LN1 x_b)
    const ushort_t* __restrict__ W1p,  // packed, 1 MB
    const ushort_t* __restrict__ W2p,  // packed, 1 MB
    const float* __restrict__ b1, const float* __restrict__ b2,
    const float* __restrict__ g, const float* __restrict__ beta,
    float* __restrict__ out, int M)
{
    __shared__ __align__(16) char smem[33280];
    ushort_t* Xs = (ushort_t*)smem;            // 8 k-tiles x 1024 us = 16 KB
    float (*epi)[260] = (float(*)[260])smem;   // 32 x 260 f32 overlay (post-loop)

    const int m0 = blockIdx.x * 32;
    const int tid = threadIdx.x;
    const int lane = tid & 63;
    const int wave = tid >> 6;
    const int l32 = lane & 31;
    const int hi  = lane >> 5;
    const bool hb = (hi != 0);

    // ---- stage X: 8 k-tiles (same as R9) ----
    {
        const int lsup = (wave & 1) * 8 + (lane >> 3);
        const int clin = lane & 7;
        const int cs = clin ^ (lsup & 7);
        int r = m0 + lsup * 2 + (cs >> 2); if (r > M - 1) r = M - 1;
        const ushort_t* xp = X + (size_t)r * 256 + (cs & 3) * 8;
        ushort_t* xl = Xs + (wave & 1) * 512;
        #pragma unroll
        for (int p = 0; p < 4; ++p) {
            const int t = p * 2 + (wave >> 1);
            gl_lds16(xp + t * 32, xl + t * 1024);
        }
    }

    // ---- X fragment offsets (row = l32, B-operand: col = l32) ----
    int aOff[2];
    {
        const int sr = l32 >> 1;
        #pragma unroll
        for (int kw = 0; kw < 2; ++kw) {
            const int q = kw * 2 + hi;
            const int slot = (((l32 & 1) << 2) | q) ^ (sr & 7);
            aOff[kw] = sr * 64 + slot * 8;
        }
    }

    f32x16 za[8] = {};
    __syncthreads();  // X staged (barrier drains vmcnt)

    for (int c = 0; c < 16; ++c) {
        // ---- stage 1: hT = w1frag(A) x xfrag(B); lane holds m=l32 column ----
        f32x16 h0 = {}, h1 = {};
        const int hcg = c * 4 + wave;
        const ushort_t* w1c = W1p + (size_t)hcg * 8192;
        #pragma unroll
        for (int t = 0; t < 8; t += 2) {
            #pragma unroll
            for (int kw = 0; kw < 2; ++kw) {
                const bf16x8 xa0 = *reinterpret_cast<const bf16x8*>(
                    Xs + t * 1024 + aOff[kw]);
                const bf16x8 xa1 = *reinterpret_cast<const bf16x8*>(
                    Xs + (t + 1) * 1024 + aOff[kw]);
                const bf16x8 wA0 = *reinterpret_cast<const bf16x8*>(
                    w1c + (t * 2 + kw) * 512 + lane * 8);
                const bf16x8 wA1 = *reinterpret_cast<const bf16x8*>(
                    w1c + ((t + 1) * 2 + kw) * 512 + lane * 8);
                h0 = __builtin_amdgcn_mfma_f32_32x32x16_bf16(wA0, xa0, h0, 0, 0, 0);
                h1 = __builtin_amdgcn_mfma_f32_32x32x16_bf16(wA1, xa1, h1, 0, 0, 0);
            }
        }

        // ---- bias + relu + pack pairs to bf16 u32 (n_local = (r&3)+8(r>>2)+4hi) ----
        float4 bq[4];
        #pragma unroll
        for (int p = 0; p < 4; ++p)
            bq[p] = *reinterpret_cast<const float4*>(b1 + hcg * 32 + p * 8 + 4 * hi);
        int pk[8];
        #pragma unroll
        for (int i = 0; i < 8; ++i) {
            const int p = i >> 1;
            const float bv0 = (i & 1) ? bq[p].z : bq[p].x;
            const float bv1 = (i & 1) ? bq[p].w : bq[p].y;
            const float v0 = fmaxf(h0[2 * i]     + h1[2 * i]     + bv0, 0.f);
            const float v1 = fmaxf(h0[2 * i + 1] + h1[2 * i + 1] + bv1, 0.f);
            pk[i] = (int)((unsigned)f2us(v0) | ((unsigned)f2us(v1) << 16));
        }
        int sw[8];
        #pragma unroll
        for (int i = 0; i < 8; ++i) sw[i] = __shfl_xor(pk[i], 32);

        // ---- assemble stage-2 A-fragments (row m=l32, k=f_local) ----
        union { int4 i4; bf16x8 v; } uf0, uf1;
        uf0.i4.x = hb ? sw[2] : pk[0];
        uf0.i4.y = hb ? sw[3] : pk[1];
        uf0.i4.z = hb ? pk[2] : sw[0];
        uf0.i4.w = hb ? pk[3] : sw[1];
        uf1.i4.x = hb ? sw[6] : pk[4];
        uf1.i4.y = hb ? sw[7] : pk[5];
        uf1.i4.z = hb ? pk[6] : sw[4];
        uf1.i4.w = hb ? pk[7] : sw[5];

        // ---- stage 2: za[nq] += h(own f-slice) @ w2 (all 256 z-cols) ----
        const ushort_t* w2c = W2p + (size_t)c * 32768;
        #pragma unroll
        for (int nq = 0; nq < 8; ++nq) {
            const bf16x8 wb0 = *reinterpret_cast<const bf16x8*>(
                w2c + ((nq * 4 + wave) * 2 + 0) * 512 + lane * 8);
            const bf16x8 wb1 = *reinterpret_cast<const bf16x8*>(
                w2c + ((nq * 4 + wave) * 2 + 1) * 512 + lane * 8);
            za[nq] = __builtin_amdgcn_mfma_f32_32x32x16_bf16(uf0.v, wb0, za[nq], 0, 0, 0);
            za[nq] = __builtin_amdgcn_mfma_f32_32x32x16_bf16(uf1.v, wb1, za[nq], 0, 0, 0);
        }
    }

    __syncthreads();  // Xs dead; epi overlay begins

    // ---- cross-wave f-reduction: 4 staggered rounds (za idx compile-time) ----
    #pragma unroll
    for (int q = 0; q < 4; ++q) {
        const int cg = (wave + q) & 3;   // col-group this wave handles this round
        #pragma unroll
        for (int nq = 0; nq < 8; ++nq) {
            if ((nq >> 1) == cg) {
                const int col = nq * 32 + l32;
                #pragma unroll
                for (int r = 0; r < 16; ++r) {
                    const int row = (r & 3) + 8 * (r >> 2) + 4 * hi;
                    float v = za[nq][r];
                    if (q) v += epi[row][col];
                    epi[row][col] = v;
                }
            }
        }
        __syncthreads();
    }

    // ---- + b2 + x resid, LN2, f32 out. 8 threads per row. ----
    const int row = tid >> 3, t8 = tid & 7;
    const int m = m0 + row;
    const int mc = (m < M) ? m : (M - 1);
    const ushort_t* xr = X + (size_t)mc * 256 + t8 * 32;
    float v[32];
    float s = 0.f, ss = 0.f;
    #pragma unroll
    for (int i = 0; i < 8; ++i) {
        const float4 e = *reinterpret_cast<const float4*>(
            &epi[row][t8 * 32 + i * 4]);
        const float4 bz = *reinterpret_cast<const float4*>(
            &b2[t8 * 32 + i * 4]);
        const int2 rb = *reinterpret_cast<const int2*>(xr + i * 4);
        const float f0 = e.x + bz.x + us2f((ushort_t)((unsigned)rb.x & 0xffffu));
        const float f1 = e.y + bz.y + us2f((ushort_t)((unsigned)rb.x >> 16));
        const float f2 = e.z + bz.z + us2f((ushort_t)((unsigned)rb.y & 0xffffu));
        const float f3 = e.w + bz.w + us2f((ushort_t)((unsigned)rb.y >> 16));
        v[i * 4]     = f0; v[i * 4 + 1] = f1;
        v[i * 4 + 2] = f2; v[i * 4 + 3] = f3;
        s  += f0 + f1 + f2 + f3;
        ss += f0 * f0 + f1 * f1 + f2 * f2 + f3 * f3;
    }
    s += __shfl_xor(s, 1); ss += __shfl_xor(ss, 1);
    s += __shfl_xor(s, 2); ss += __shfl_xor(ss, 2);
    s += __shfl_xor(s, 4); ss += __shfl_xor(ss, 4);
    const float mean = s * (1.f / 256.f);
    const float var = ss * (1.f / 256.f) - mean * mean;
    const float rs = rsqrtf(var + 1e-5f);
    if (m < M) {
        #pragma unroll
        for (int i = 0; i < 8; ++i) {
            const float4 g4 = *reinterpret_cast<const float4*>(
                &g[t8 * 32 + i * 4]);
            const float4 b4 = *reinterpret_cast<const float4*>(
                &beta[t8 * 32 + i * 4]);
            float4 o4;
            o4.x = (v[i * 4]     - mean) * rs * g4.x + b4.x;
            o4.y = (v[i * 4 + 1] - mean) * rs * g4.y + b4.y;
            o4.z = (v[i * 4 + 2] - mean) * rs * g4.z + b4.z;
            o4.w = (v[i * 4 + 3] - mean) * rs * g4.w + b4.w;
            *reinterpret_cast<float4*>(
                &out[(size_t)m * 256 + t8 * 32 + i * 4]) = o4;
        }
    }
}

// ---------------------------------------------------------------------------
// MS-deformable attention v7 (unchanged — at structural gather limit).
// ---------------------------------------------------------------------------
__global__ __launch_bounds__(256) void msda_kernel_v7(
    const ushort_t* __restrict__ og,     // [M,480] bf16: offs 0..319, logits 320..479
    const float* __restrict__ refp,      // [M,10]
    const ushort_t* __restrict__ value,  // [M,256] bf16 = (B,L,H,32)
    bf16* __restrict__ out,              // [M,256] bf16
    int M, int L)
{
    const int tid = threadIdx.x;
    const int nb = gridDim.x;
    int wk = blockIdx.x;
    if ((nb & 7) == 0) {                       // bijective XCD remap
        const int per = nb >> 3;
        wk = (blockIdx.x & 7) * per + (blockIdx.x >> 3);
    }
    const int qbase = wk * 8;

    __shared__ float s_attn[8][160];   // 5120 B
    __shared__ int2  s_off[1280];      // 10240 B
    __shared__ int2  s_wh[1280];       // 10240 B -> total 25600 B

    for (int i = tid; i < 1280; i += 256) {
        int q = i / 160, j = i - q * 160;
        int qq = qbase + q;
        s_attn[q][j] = (qq < M) ? us2f(og[(size_t)qq * 480 + 320 + j]) : 0.f;
    }
    __syncthreads();

    if (tid < 64) {
        float* a = &s_attn[tid >> 3][(tid & 7) * 20];
        float mx = -1e30f;
        #pragma unroll
        for (int i = 0; i < 20; ++i) mx = fmaxf(mx, a[i]);
        float ssum = 0.f;
        #pragma unroll
        for (int i = 0; i < 20; ++i) {
            float e = __expf(a[i] - mx);
            a[i] = e;
            ssum += e;
        }
        float inv = 1.f / ssum;
        #pragma unroll
        for (int i = 0; i < 20; ++i) a[i] *= inv;
    }
    __syncthreads();

    #pragma unroll
    for (int it = 0; it < 5; ++it) {
        const int t = tid + it * 256;
        const int q  = t / 160;
        const int r  = t - q * 160;
        const int l  = (r - (r / 20) * 20) >> 2;
        const int qq = qbase + q;

        int2 offp = {0, 0};
        __half2 h01 = __floats2half2_rn(0.f, 0.f);
        __half2 h23 = h01;
        if (qq < M) {
            const int Wi = (l == 0) ? 100 : (l == 1) ? 50 : (l == 2) ? 25
                         : (l == 3) ? 13 : 7;
            const int s0 = (l == 0) ? 0 : (l == 1) ? 10000 : (l == 2) ? 12500
                         : (l == 3) ? 13125 : 13294;
            const float Wf = (float)Wi;
            const float ox = us2f(og[(size_t)qq * 480 + r * 2]);
            const float oy = us2f(og[(size_t)qq * 480 + r * 2 + 1]);
            const float2 rf = *reinterpret_cast<const float2*>(
                &refp[(size_t)qq * 10 + l * 2]);
            const float a = s_attn[q][r];

            const float px = fmaf(rf.x, Wf, -0.5f) + ox;
            const float py = fmaf(rf.y, Wf, -0.5f) + oy;
            const float x0f = floorf(px);
            const float y0f = floorf(py);
            const float lx = px - x0f;
            const float ly = py - y0f;
            const int x0 = (int)x0f;
            const int y0 = (int)y0f;

            const float wx0v = (x0 >= 0 && x0 < Wi) ? (1.f - lx) : 0.f;
            const float wx1v = (x0 + 1 >= 0 && x0 + 1 < Wi) ? lx : 0.f;
            const float wy0v = (y0 >= 0 && y0 < Wi) ? (1.f - ly) : 0.f;
            const float wy1v = (y0 + 1 >= 0 && y0 + 1 < Wi) ? ly : 0.f;

            const int c0 = min(max(x0, 0), Wi - 2);
            const int r0 = min(max(y0, 0), Wi - 2);
            const float swx0 = (x0 == c0 ? wx0v : 0.f) + (x0 + 1 == c0 ? wx1v : 0.f);
            const float swx1 = (x0 == c0 + 1 ? wx0v : 0.f) + (x0 + 1 == c0 + 1 ? wx1v : 0.f);
            const float swy0 = (y0 == r0 ? wy0v : 0.f) + (y0 + 1 == r0 ? wy1v : 0.f);
            const float swy1 = (y0 == r0 + 1 ? wy0v : 0.f) + (y0 + 1 == r0 + 1 ? wy1v : 0.f);

            offp.x = (s0 + r0 * Wi + c0) * 512;
            offp.y = offp.x + Wi * 512;
            h01 = __floats2half2_rn(a * swx0 * swy0, a * swx1 * swy0);
            h23 = __floats2half2_rn(a * swx0 * swy1, a * swx1 * swy1);
        }
        s_off[t] = offp;
        union { __half2 h; int i; } c0u, c1u;
        c0u.h = h01; c1u.h = h23;
        int2 wpk; wpk.x = c0u.i; wpk.y = c1u.i;
        s_wh[t] = wpk;
    }
    __syncthreads();

    const int qi  = tid >> 5;
    const int g   = tid & 31;
    const int h   = g >> 2;
    const int sub = g & 3;
    const int bq = qbase + qi;
    if (bq >= M) return;
    const int b = bq / L;

    const char* vb = (const char*)value + (size_t)b * L * 512 + h * 64 + sub * 16;

    float acc[8] = {};
    const int tb = qi * 160 + h * 20;
    #pragma unroll 2
    for (int p = 0; p < 20; ++p) {
        const int2 off = s_off[tb + p];
        const int2 whp = s_wh[tb + p];
        const int4 u00 = *reinterpret_cast<const int4*>(vb + off.x);
        const int4 u10 = *reinterpret_cast<const int4*>(vb + off.x + 512);
        const int4 u01 = *reinterpret_cast<const int4*>(vb + off.y);
        const int4 u11 = *reinterpret_cast<const int4*>(vb + off.y + 512);
        union { int i; __half2 h; } w0u, w1u;
        w0u.i = whp.x; w1u.i = whp.y;
        const float2 w01 = __half22float2(w0u.h);
        const float2 w23 = __half22float2(w1u.h);
        #define ACC4(u, wt)                                                        \
            acc[0] = fmaf(wt, __uint_as_float((unsigned)(u).x << 16), acc[0]);      \
            acc[1] = fmaf(wt, __uint_as_float((unsigned)(u).x & 0xffff0000u), acc[1]); \
            acc[2] = fmaf(wt, __uint_as_float((unsigned)(u).y << 16), acc[2]);      \
            acc[3] = fmaf(wt, __uint_as_float((unsigned)(u).y & 0xffff0000u), acc[3]); \
            acc[4] = fmaf(wt, __uint_as_float((unsigned)(u).z << 16), acc[4]);      \
            acc[5] = fmaf(wt, __uint_as_float((unsigned)(u).z & 0xffff0000u), acc[5]); \
            acc[6] = fmaf(wt, __uint_as_float((unsigned)(u).w << 16), acc[6]);      \
            acc[7] = fmaf(wt, __uint_as_float((unsigned)(u).w & 0xffff0000u), acc[7]);
        ACC4(u00, w01.x)
        ACC4(u10, w01.y)
        ACC4(u01, w23.x)
        ACC4(u11, w23.y)
        #undef ACC4
    }

    ushort_t o[8];
    #pragma unroll
    for (int i = 0; i < 8; ++i) o[i] = f2us(acc[i]);
    int4 pkt;
    pkt.x = (int)o[0] | ((int)o[1] << 16);
    pkt.y = (int)o[2] | ((int)o[3] << 16);
    pkt.z = (int)o[4] | ((int)o[5] << 16);
    pkt.w = (int)o[6] | ((int)o[7] << 16);
    *reinterpret_cast<int4*>((ushort_t*)out + (size_t)bq * 256 + h * 32 + sub * 8) = pkt;
}

// ---------------------------------------------------------------------------
// LayerNorm over 256, bf16 input -> bf16 out (LN1).
// ---------------------------------------------------------------------------
template<bool OUT_BF16>
__global__ __launch_bounds__(256) void ln_kernel(
    const ushort_t* __restrict__ yb, const float* __restrict__ g,
    const float* __restrict__ bta, void* __restrict__ outv, int M)
{
    const int wave = threadIdx.x >> 6, lane = threadIdx.x & 63;
    const int row = blockIdx.x * 4 + wave;
    if (row >= M) return;
    const int2 raw = *reinterpret_cast<const int2*>(&yb[(size_t)row * 256 + lane * 4]);
    float v0 = us2f((ushort_t)((unsigned)raw.x & 0xffffu));
    float v1 = us2f((ushort_t)((unsigned)raw.x >> 16));
    float v2 = us2f((ushort_t)((unsigned)raw.y & 0xffffu));
    float v3 = us2f((ushort_t)((unsigned)raw.y >> 16));
    float s  = v0 + v1 + v2 + v3;
    float ss = v0 * v0 + v1 * v1 + v2 * v2 + v3 * v3;
    #pragma unroll
    for (int o = 32; o > 0; o >>= 1) {
        s += __shfl_down(s, o);
        ss += __shfl_down(ss, o);
    }
    s = __shfl(s, 0);
    ss = __shfl(ss, 0);
    const float mean = s * (1.f / 256.f);
    const float var = ss * (1.f / 256.f) - mean * mean;
    const float rs = rsqrtf(var + 1e-5f);
    const float4 g4 = *reinterpret_cast<const float4*>(&g[lane * 4]);
    const float4 b4 = *reinterpret_cast<const float4*>(&bta[lane * 4]);
    float4 o4;
    o4.x = (v0 - mean) * rs * g4.x + b4.x;
    o4.y = (v1 - mean) * rs * g4.y + b4.y;
    o4.z = (v2 - mean) * rs * g4.z + b4.z;
    o4.w = (v3 - mean) * rs * g4.w + b4.w;
    if (OUT_BF16) {
        int2 pk;
        pk.x = (unsigned)f2us(o4.x) | ((unsigned)f2us(o4.y) << 16);
        pk.y = (unsigned)f2us(o4.z) | ((unsigned)f2us(o4.w) << 16);
        *reinterpret_cast<int2*>((ushort_t*)outv + (size_t)row * 256 + lane * 4) = pk;
    } else {
        *reinterpret_cast<float4*>((float*)outv + (size_t)row * 256 + lane * 4) = o4;
    }
}

// ---------------------------------------------------------------------------
extern "C" void kernel_launch(void* const* d_in, const int* in_sizes, int n_in,
                              void* d_out, int out_size, void* d_ws, size_t ws_size,
                              hipStream_t stream)
{
    const int B = 2, L = 13343, C = 256;
    const int M = B * L;  // 26686

    const float* src  = (const float*)d_in[0];
    const float* pos  = (const float*)d_in[1];
    const float* refp = (const float*)d_in[2];
    const float* wv   = (const float*)d_in[3];
    const float* bv   = (const float*)d_in[4];
    const float* wo   = (const float*)d_in[5];
    const float* bo   = (const float*)d_in[6];
    const float* wa   = (const float*)d_in[7];
    const float* ba   = (const float*)d_in[8];
    const float* wout = (const float*)d_in[9];
    const float* bout = (const float*)d_in[10];
    const float* ln1g = (const float*)d_in[11];
    const float* ln1b = (const float*)d_in[12];
    const float* w1   = (const float*)d_in[13];
    const float* b1   = (const float*)d_in[14];
    const float* w2   = (const float*)d_in[15];
    const float* b2   = (const float*)d_in[16];
    const float* ln2g = (const float*)d_in[17];
    const float* ln2b = (const float*)d_in[18];

    char* ws = (char*)d_ws;
    const size_t MB = 1ull << 20;
    // ---- workspace overlay ----
    bf16*  src_b  = (bf16*)(ws + 0);         // 13.7 MB
    bf16*  q_b    = (bf16*)(ws + 14 * MB);   // 13.7
    bf16*  val_b  = (bf16*)(ws + 28 * MB);   // 13.7
    bf16*  og     = (bf16*)(ws + 42 * MB);   // M*480 bf16 = 25.6 -> ends 67.6
    bf16*  acc_b  = (bf16*)(ws + 95 * MB);   // 13.7 -> ends 108.7
    bf16*  y      = (bf16*)(ws + 110 * MB);  // 13.7 bf16 (dead after LN1)
    bf16*  x_b    = (bf16*)(ws + 138 * MB);  // 13.7 (LN1 out, FFN input+resid)
    bf16* wvt    = (bf16*)(ws + 152 * MB);   // 256*256
    bf16* wcat   = wvt + 256 * 256;          // 480*256
    bf16* woutt  = wcat + 480 * 256;         // 256*256
    ushort_t* w1p = (ushort_t*)(woutt + 256 * 256);  // packed, 2048*256
    ushort_t* w2p = w1p + 2048 * 256;                // packed, 256*2048
    float* bcat  = (float*)(w2p + 256 * 2048);       // 480 f32
    (void)ws_size; (void)n_in; (void)in_sizes; (void)out_size;

    const int mt64  = (M + 63) / 64;        // 417
    const int gm8   = (mt64 + 7) / 8;       // 53
    const int mt128 = (M + 127) / 128;      // 209
    const int gb8   = (mt128 + 7) / 8;      // 27
    const int mt32  = (M + 31) / 32;        // 834
    const int lnb   = (M + 3) / 4;          // 6672

    // ---- fused weight prep (one launch; w1/w2 packed fragment-major) ----
    prep_kernel<<<1274, 256, 0, stream>>>(wv, wo, wa, wout, w1, w2, bo, ba,
                                          wvt, wcat, woutt, w1p, w2p, bcat);

    // ---- fused activation casts (float4) ----
    cast2_kernel<<<(M * C / 4 + 255) / 256, 256, 0, stream>>>(
        src, pos, src_b, q_b, M * C);

    // value = src @ wv + bv  (bf16)  [small kernel, NT=2]
    gemm_mfma_s<false, true, false, false, 2, 4><<<gm8 * 16, 256, 0, stream>>>(
        (const ushort_t*)src_b, (const ushort_t*)wvt, bv, nullptr, val_b,
        M, 256, 256, mt64);

    // og = q @ [wo|wa] + [bo|ba]  (bf16, N=480)  [BIG kernel, NT=4]
    gemm_mfma_b<false, true, false, false, 4><<<gb8 * 32, 256, 0, stream>>>(
        (const ushort_t*)q_b, (const ushort_t*)wcat, bcat, nullptr, og,
        M, 480, 256, mt128);

    // deformable attention -> acc_b (bf16)  [batch->XCD remap]
    msda_kernel_v7<<<(M + 7) / 8, 256, 0, stream>>>(
        (const ushort_t*)og, refp, (const ushort_t*)val_b, acc_b, M, L);

    // y = acc @ wout + bout + src  (bf16 out, f32 resid)  [small kernel, NT=2]
    gemm_mfma_s<false, true, true, false, 2, 4><<<gm8 * 16, 256, 0, stream>>>(
        (const ushort_t*)acc_b, (const ushort_t*)woutt, bout, src, y,
        M, 256, 256, mt64);

    // x_b = LN1(y)  (bf16 in, bf16 out)
    ln_kernel<true><<<lnb, 256, 0, stream>>>(
        (const ushort_t*)y, ln1g, ln1b, x_b, M);

    // out = LN2( x + relu(x@w1+b1)@w2 + b2 )  — FUSED v3 (register-resident h)
    ffn_fused3<<<mt32, 256, 0, stream>>>(
        (const ushort_t*)x_b, w1p, w2p, b1, b2, ln2g, ln2b,
        (float*)d_out, M);
}

// Round 11
// 356.933 us; speedup vs baseline: 1.3056x; 1.3056x over previous
//
#include <hip/hip_runtime.h>
#include <hip/hip_bf16.h>
#include <hip/hip_fp16.h>

typedef __hip_bfloat16 bf16;
typedef unsigned short ushort_t;
typedef __attribute__((ext_vector_type(8))) short bf16x8;
typedef __attribute__((ext_vector_type(16))) float f32x16;

__device__ __forceinline__ float us2f(unsigned short u) {
    unsigned int x = ((unsigned int)u) << 16;
    return __uint_as_float(x);
}
__device__ __forceinline__ ushort_t f2us(float f) {
    return ((__hip_bfloat16_raw)__float2bfloat16(f)).x;
}

// async global->LDS, 16 B per lane. LDS dest = wave-uniform base + lane*16.
__device__ __forceinline__ void gl_lds16(const ushort_t* g, ushort_t* l) {
    __builtin_amdgcn_global_load_lds(
        (const __attribute__((address_space(1))) void*)g,
        (__attribute__((address_space(3))) void*)l, 16, 0, 0);
}

// ---------------------------------------------------------------------------
// Fused input cast (float4): src_b = bf16(src), q_b = bf16(src + pos)
// ---------------------------------------------------------------------------
__global__ __launch_bounds__(256) void cast2_kernel(
    const float* __restrict__ src, const float* __restrict__ pos,
    bf16* __restrict__ src_b, bf16* __restrict__ q_b, int n)
{
    int i = (blockIdx.x * 256 + threadIdx.x) * 4;
    if (i < n) {
        const float4 s4 = *reinterpret_cast<const float4*>(&src[i]);
        const float4 p4 = *reinterpret_cast<const float4*>(&pos[i]);
        int2 sp, qp;
        sp.x = (unsigned)f2us(s4.x) | ((unsigned)f2us(s4.y) << 16);
        sp.y = (unsigned)f2us(s4.z) | ((unsigned)f2us(s4.w) << 16);
        qp.x = (unsigned)f2us(s4.x + p4.x) | ((unsigned)f2us(s4.y + p4.y) << 16);
        qp.y = (unsigned)f2us(s4.z + p4.z) | ((unsigned)f2us(s4.w + p4.w) << 16);
        *reinterpret_cast<int2*>((ushort_t*)src_b + i) = sp;
        *reinterpret_cast<int2*>((ushort_t*)q_b + i) = qp;
    }
}

// ---------------------------------------------------------------------------
// Fused weight prep. Small weights: transpose-cast to [N][K] bf16.
// w1/w2: packed FRAGMENT-MAJOR (unchanged from R9):
//   w1p (hcg,t,kw,lane): 16 B = w1[k=t*32+kw*16+(l>>5)*8+e][n=hcg*32+(l&31)]
//   w2p (c,nq,t,kw,lane): w2[f=c*128+t*32+kw*16+(l>>5)*8+e][n=nq*32+(l&31)]
// ---------------------------------------------------------------------------
__global__ __launch_bounds__(256) void prep_kernel(
    const float* __restrict__ wv, const float* __restrict__ wo,
    const float* __restrict__ wa, const float* __restrict__ wout,
    const float* __restrict__ w1, const float* __restrict__ w2,
    const float* __restrict__ bo, const float* __restrict__ ba,
    bf16* __restrict__ wvt, bf16* __restrict__ wcat, bf16* __restrict__ woutt,
    ushort_t* __restrict__ w1p, ushort_t* __restrict__ w2p,
    float* __restrict__ bcat)
{
    __shared__ float tile[32][33];
    const int b = blockIdx.x;
    const float* W; bf16* Wt = nullptr; ushort_t* Wp = nullptr;
    int K, N, tb, mode = 0;
    if (b < 64)        { W = wv;   Wt = wvt;            K = 256;  N = 256;  tb = b; }
    else if (b < 144)  { W = wo;   Wt = wcat;           K = 256;  N = 320;  tb = b - 64; }
    else if (b < 184)  { W = wa;   Wt = wcat + 320*256; K = 256;  N = 160;  tb = b - 144; }
    else if (b < 248)  { W = wout; Wt = woutt;          K = 256;  N = 256;  tb = b - 184; }
    else if (b < 760)  { W = w1;   Wp = w1p; mode = 1;  K = 256;  N = 2048; tb = b - 248; }
    else if (b < 1272) { W = w2;   Wp = w2p; mode = 2;  K = 2048; N = 256;  tb = b - 760; }
    else {
        int i = (b - 1272) * 256 + threadIdx.x;
        if (i < 320) bcat[i] = bo[i];
        else if (i < 480) bcat[i] = ba[i - 320];
        return;
    }
    const int ntn = N >> 5;
    const int nb = (tb % ntn) * 32, kb = (tb / ntn) * 32;
    const int tx = threadIdx.x & 31, ty = threadIdx.x >> 5;  // 32 x 8
    #pragma unroll
    for (int i = 0; i < 32; i += 8) {
        int k = kb + ty + i, n = nb + tx;
        tile[ty + i][tx] = (k < K && n < N) ? W[(size_t)k * N + n] : 0.f;
    }
    __syncthreads();
    if (mode == 0) {
        #pragma unroll
        for (int i = 0; i < 32; i += 8) {
            int n = nb + ty + i, k = kb + tx;
            if (n < N && k < K)
                Wt[(size_t)n * K + k] = __float2bfloat16(tile[tx][ty + i]);
        }
    } else if (threadIdx.x < 128) {
        const int l = threadIdx.x & 63, kw = threadIdx.x >> 6;
        const int kb8 = kw * 16 + (l >> 5) * 8;
        const int nx = l & 31;
        ushort_t tmp[8];
        #pragma unroll
        for (int e = 0; e < 8; ++e) tmp[e] = f2us(tile[kb8 + e][nx]);
        size_t base;
        if (mode == 1)
            base = ((size_t)(((nb >> 5) * 8 + (kb >> 5)) * 2 + kw)) * 512;
        else
            base = ((size_t)((((kb >> 7) * 8 + (nb >> 5)) * 4 + ((kb >> 5) & 3)) * 2 + kw)) * 512;
        *reinterpret_cast<int4*>(Wp + base + l * 8) =
            *reinterpret_cast<const int4*>(tmp);
    }
}

// ---------------------------------------------------------------------------
// MFMA bf16 GEMM (64x128 tile, M-split), swizzled-LDS, double-buffered.
// (proven R5/R6 kernel — used for the N=256,K=256 GEMMs: value, wout)
// ---------------------------------------------------------------------------
template<bool RELU, bool OUT_BF16, bool HAS_RESID, bool RESID_BF16, int NT, int WPE>
__global__ __launch_bounds__(256, WPE) void gemm_mfma_s(
    const ushort_t* __restrict__ A,    // [M][K] bf16
    const ushort_t* __restrict__ Bt,   // [N][K] bf16
    const float* __restrict__ bias,    // [N] f32
    const void* __restrict__ residv,   // [M][N] f32 or bf16
    void* __restrict__ outv, int M, int N, int K, int mtiles)
{
    __shared__ __align__(16) char smemraw[24576];
    ushort_t* Asmem = (ushort_t*)smemraw;
    ushort_t* Bsmem = (ushort_t*)(smemraw + 4096);
    float (*epi)[68] = (float(*)[68])smemraw;

    const int lid = blockIdx.x;
    const int tbk = lid >> 3;
    const int xb = tbk & (NT - 1);
    const int yg = (tbk / NT) * 8 + (lid & 7);
    if (yg >= mtiles) return;
    const int m0 = yg * 64;
    const int n0 = xb * 128;

    const int tid = threadIdx.x;
    const int lane = tid & 63;
    const int wave = tid >> 6;
    const int l32 = lane & 31;
    const int hi  = lane >> 5;
    const int wm = wave >> 1;
    const int wn = wave & 1;

    const int lsup = lane >> 3;
    const int clin = lane & 7;

    const int gsA = wave * 8 + lsup;
    const int csA = clin ^ (gsA & 7);
    int rA = m0 + gsA * 2 + (csA >> 2); if (rA > M - 1) rA = M - 1;
    const ushort_t* aP = A + (size_t)rA * K + (csA & 3) * 8;
    ushort_t* aL = Asmem + wave * 512;

    const ushort_t* bP[2]; ushort_t* bL[2];
    #pragma unroll
    for (int i = 0; i < 2; ++i) {
        const int gsB = wave * 16 + i * 8 + lsup;
        const int csB = clin ^ (gsB & 7);
        int rB = n0 + gsB * 2 + (csB >> 2); if (rB > N - 1) rB = N - 1;
        bP[i] = Bt + (size_t)rB * K + (csB & 3) * 8;
        bL[i] = Bsmem + (wave * 16 + i * 8) * 64;
    }

    const int arow = wm * 32 + l32;
    const int asup = arow >> 1;
    const ushort_t* aR[2];
    #pragma unroll
    for (int kw = 0; kw < 2; ++kw) {
        const int q = kw * 2 + hi;
        const int slot = (((arow & 1) << 2) | q) ^ (asup & 7);
        aR[kw] = Asmem + asup * 64 + slot * 8;
    }
    const ushort_t* bR[2][2];
    #pragma unroll
    for (int j = 0; j < 2; ++j) {
        const int brow = wn * 64 + j * 32 + l32;
        const int bsup = brow >> 1;
        #pragma unroll
        for (int kw = 0; kw < 2; ++kw) {
            const int q = kw * 2 + hi;
            const int slot = (((brow & 1) << 2) | q) ^ (bsup & 7);
            bR[j][kw] = Bsmem + bsup * 64 + slot * 8;
        }
    }

    f32x16 acc[2] = {};

    auto stage = [&](int ofs) {
        gl_lds16(aP, aL + ofs);             aP    += 32;
        gl_lds16(bP[0], bL[0] + ofs);       bP[0] += 32;
        gl_lds16(bP[1], bL[1] + ofs);       bP[1] += 32;
    };
    auto compute = [&](int ofs) {
        #pragma unroll
        for (int kw = 0; kw < 2; ++kw) {
            const bf16x8 af = *reinterpret_cast<const bf16x8*>(aR[kw] + ofs);
            #pragma unroll
            for (int j = 0; j < 2; ++j)
                acc[j] = __builtin_amdgcn_mfma_f32_32x32x16_bf16(
                    af, *reinterpret_cast<const bf16x8*>(bR[j][kw] + ofs),
                    acc[j], 0, 0, 0);
        }
    };

    const int ntile = K >> 5;
    stage(0);
    for (int t = 0; t < ntile; t += 2) {
        __syncthreads();
        stage(6144);
        compute(0);
        __syncthreads();
        if (t + 2 < ntile) stage(0);
        compute(6144);
    }
    __syncthreads();

    #pragma unroll
    for (int half = 0; half < 2; ++half) {
        if (wn == half) {
            #pragma unroll
            for (int j = 0; j < 2; ++j) {
                const int coll = j * 32 + l32;
                const int n = n0 + half * 64 + coll;
                const float bv = (n < N) ? bias[n] : 0.f;
                #pragma unroll
                for (int r = 0; r < 16; ++r) {
                    const int row = wm * 32 + hi * 4 + (r & 3) + (r >> 2) * 8;
                    epi[row][coll] = acc[j][r] + bv;
                }
            }
        }
        __syncthreads();
        #pragma unroll
        for (int i = 0; i < 4; ++i) {
            const int idx = i * 256 + tid;
            const int row = idx >> 4;
            const int c4  = idx & 15;
            const int m = m0 + row;
            const int n = n0 + half * 64 + c4 * 4;
            if (m < M && n + 3 < N) {
                float4 v = *reinterpret_cast<const float4*>(&epi[row][c4 * 4]);
                if (HAS_RESID) {
                    if (RESID_BF16) {
                        const int2 rw = *reinterpret_cast<const int2*>(
                            (const ushort_t*)residv + (size_t)m * N + n);
                        v.x += us2f((ushort_t)((unsigned)rw.x & 0xffffu));
                        v.y += us2f((ushort_t)((unsigned)rw.x >> 16));
                        v.z += us2f((ushort_t)((unsigned)rw.y & 0xffffu));
                        v.w += us2f((ushort_t)((unsigned)rw.y >> 16));
                    } else {
                        const float4 r4 = *reinterpret_cast<const float4*>(
                            (const float*)residv + (size_t)m * N + n);
                        v.x += r4.x; v.y += r4.y; v.z += r4.z; v.w += r4.w;
                    }
                }
                if (RELU) {
                    v.x = fmaxf(v.x, 0.f); v.y = fmaxf(v.y, 0.f);
                    v.z = fmaxf(v.z, 0.f); v.w = fmaxf(v.w, 0.f);
                }
                if (OUT_BF16) {
                    int2 pk;
                    pk.x = (unsigned)f2us(v.x) | ((unsigned)f2us(v.y) << 16);
                    pk.y = (unsigned)f2us(v.z) | ((unsigned)f2us(v.w) << 16);
                    *reinterpret_cast<int2*>((ushort_t*)outv + (size_t)m * N + n) = pk;
                } else {
                    *reinterpret_cast<float4*>((float*)outv + (size_t)m * N + n) = v;
                }
            }
        }
        if (half == 0) __syncthreads();
    }
}

// ---------------------------------------------------------------------------
// BIG MFMA bf16 GEMM: 128x128 tile (proven R7 kernel — used for og, N=480).
// ---------------------------------------------------------------------------
template<bool RELU, bool OUT_BF16, bool HAS_RESID, bool RESID_BF16, int NT>
__global__ __launch_bounds__(256, 4) void gemm_mfma_b(
    const ushort_t* __restrict__ A,    // [M][K] bf16
    const ushort_t* __restrict__ Bt,   // [N][K] bf16
    const float* __restrict__ bias,    // [N] f32
    const void* __restrict__ residv,   // [M][N] f32 or bf16
    void* __restrict__ outv, int M, int N, int K, int mtiles)
{
    __shared__ __align__(16) char smemraw[32768];
    ushort_t* Asmem = (ushort_t*)smemraw;
    ushort_t* Bsmem = (ushort_t*)(smemraw + 8192);
    float (*epi)[68] = (float(*)[68])smemraw;

    const int lid = blockIdx.x;
    const int tbk = lid >> 3;
    const int xb = tbk & (NT - 1);
    const int yg = (tbk / NT) * 8 + (lid & 7);
    if (yg >= mtiles) return;
    const int m0 = yg * 128;
    const int n0 = xb * 128;

    const int tid = threadIdx.x;
    const int lane = tid & 63;
    const int wave = tid >> 6;
    const int l32 = lane & 31;
    const int hi  = lane >> 5;
    const int wm = wave >> 1;
    const int wn = wave & 1;

    const int lsup = lane >> 3;
    const int clin = lane & 7;
    const ushort_t *aP[2], *bP[2];
    ushort_t *aL[2], *bL[2];
    #pragma unroll
    for (int i = 0; i < 2; ++i) {
        const int gs = wave * 16 + i * 8 + lsup;
        const int cs = clin ^ (gs & 7);
        int rA = m0 + gs * 2 + (cs >> 2); if (rA > M - 1) rA = M - 1;
        aP[i] = A + (size_t)rA * K + (cs & 3) * 8;
        aL[i] = Asmem + (wave * 16 + i * 8) * 64;
        int rB = n0 + gs * 2 + (cs >> 2); if (rB > N - 1) rB = N - 1;
        bP[i] = Bt + (size_t)rB * K + (cs & 3) * 8;
        bL[i] = Bsmem + (wave * 16 + i * 8) * 64;
    }

    const ushort_t* aR[2][2];
    const ushort_t* bR[2][2];
    #pragma unroll
    for (int mi = 0; mi < 2; ++mi) {
        const int arow = wm * 64 + mi * 32 + l32;
        const int asup = arow >> 1;
        #pragma unroll
        for (int kw = 0; kw < 2; ++kw) {
            const int q = kw * 2 + hi;
            const int slot = (((arow & 1) << 2) | q) ^ (asup & 7);
            aR[mi][kw] = Asmem + asup * 64 + slot * 8;
        }
    }
    #pragma unroll
    for (int ni = 0; ni < 2; ++ni) {
        const int brow = wn * 64 + ni * 32 + l32;
        const int bsup = brow >> 1;
        #pragma unroll
        for (int kw = 0; kw < 2; ++kw) {
            const int q = kw * 2 + hi;
            const int slot = (((brow & 1) << 2) | q) ^ (bsup & 7);
            bR[ni][kw] = Bsmem + bsup * 64 + slot * 8;
        }
    }

    f32x16 a00 = {}, a01 = {}, a10 = {}, a11 = {};

    auto stage = [&](int ofs) {
        gl_lds16(aP[0], aL[0] + ofs); aP[0] += 32;
        gl_lds16(aP[1], aL[1] + ofs); aP[1] += 32;
        gl_lds16(bP[0], bL[0] + ofs); bP[0] += 32;
        gl_lds16(bP[1], bL[1] + ofs); bP[1] += 32;
    };
    auto compute = [&](int ofs) {
        #pragma unroll
        for (int kw = 0; kw < 2; ++kw) {
            const bf16x8 af0 = *reinterpret_cast<const bf16x8*>(aR[0][kw] + ofs);
            const bf16x8 af1 = *reinterpret_cast<const bf16x8*>(aR[1][kw] + ofs);
            const bf16x8 bf0 = *reinterpret_cast<const bf16x8*>(bR[0][kw] + ofs);
            const bf16x8 bf1 = *reinterpret_cast<const bf16x8*>(bR[1][kw] + ofs);
            a00 = __builtin_amdgcn_mfma_f32_32x32x16_bf16(af0, bf0, a00, 0, 0, 0);
            a01 = __builtin_amdgcn_mfma_f32_32x32x16_bf16(af0, bf1, a01, 0, 0, 0);
            a10 = __builtin_amdgcn_mfma_f32_32x32x16_bf16(af1, bf0, a10, 0, 0, 0);
            a11 = __builtin_amdgcn_mfma_f32_32x32x16_bf16(af1, bf1, a11, 0, 0, 0);
        }
    };

    const int ntile = K >> 5;
    stage(0);
    for (int t = 0; t < ntile; t += 2) {
        __syncthreads();
        stage(8192);
        compute(0);
        __syncthreads();
        if (t + 2 < ntile) stage(0);
        compute(8192);
    }
    __syncthreads();

    #pragma unroll
    for (int qd = 0; qd < 4; ++qd) {
        const int rh = qd >> 1, ch = qd & 1;
        if (qd) __syncthreads();
        if (wm == rh && wn == ch) {
            #pragma unroll
            for (int ni = 0; ni < 2; ++ni) {
                const int col = ni * 32 + l32;
                const int n = n0 + ch * 64 + col;
                const float bv = (n < N) ? bias[n] : 0.f;
                #pragma unroll
                for (int mi = 0; mi < 2; ++mi) {
                    const f32x16& ac = (mi == 0) ? (ni == 0 ? a00 : a01)
                                                 : (ni == 0 ? a10 : a11);
                    #pragma unroll
                    for (int r = 0; r < 16; ++r) {
                        const int row = mi * 32 + hi * 4 + (r & 3) + (r >> 2) * 8;
                        epi[row][col] = ac[r] + bv;
                    }
                }
            }
        }
        __syncthreads();
        #pragma unroll
        for (int i = 0; i < 4; ++i) {
            const int idx = i * 256 + tid;
            const int row = idx >> 4;
            const int c4  = idx & 15;
            const int m = m0 + rh * 64 + row;
            const int n = n0 + ch * 64 + c4 * 4;
            if (m < M && n + 3 < N) {
                float4 v = *reinterpret_cast<const float4*>(&epi[row][c4 * 4]);
                if (HAS_RESID) {
                    if (RESID_BF16) {
                        const int2 rw = *reinterpret_cast<const int2*>(
                            (const ushort_t*)residv + (size_t)m * N + n);
                        v.x += us2f((ushort_t)((unsigned)rw.x & 0xffffu));
                        v.y += us2f((ushort_t)((unsigned)rw.x >> 16));
                        v.z += us2f((ushort_t)((unsigned)rw.y & 0xffffu));
                        v.w += us2f((ushort_t)((unsigned)rw.y >> 16));
                    } else {
                        const float4 r4 = *reinterpret_cast<const float4*>(
                            (const float*)residv + (size_t)m * N + n);
                        v.x += r4.x; v.y += r4.y; v.z += r4.z; v.w += r4.w;
                    }
                }
                if (RELU) {
                    v.x = fmaxf(v.x, 0.f); v.y = fmaxf(v.y, 0.f);
                    v.z = fmaxf(v.z, 0.f); v.w = fmaxf(v.w, 0.f);
                }
                if (OUT_BF16) {
                    int2 pk;
                    pk.x = (unsigned)f2us(v.x) | ((unsigned)f2us(v.y) << 16);
                    pk.y = (unsigned)f2us(v.z) | ((unsigned)f2us(v.w) << 16);
                    *reinterpret_cast<int2*>((ushort_t*)outv + (size_t)m * N + n) = pk;
                } else {
                    *reinterpret_cast<float4*>((float*)outv + (size_t)m * N + n) = v;
                }
            }
        }
    }
}

// ---------------------------------------------------------------------------
// FUSED FFN v4 = v3's swapped-operand stage-1 (hT, verified R10) + packed-u32
// h-store into slot-XOR-swizzled Hs[m][f] + v2's stage-2/epilogue (verified
// R9, 1x w2 traffic, za0/za1 per wave).  Hs addressing:
//   Hs[m][f] at ushort  m*128 + ((f>>3) ^ (m&15))*8 + (f&7)
// Writes: 8 ds_write_b32/thread (<=4-way conflict); reads: ds_read_b128,
// 2-way (free).  Zero shfl chains, 2 barriers/chunk, LDS 33280 B, (256,3).
// ---------------------------------------------------------------------------
__global__ __launch_bounds__(256, 3) void ffn_fused4(
    const ushort_t* __restrict__ X,    // [M][256] bf16 (post-LN1 x_b)
    const ushort_t* __restrict__ W1p,  // packed, 1 MB
    const ushort_t* __restrict__ W2p,  // packed, 1 MB
    const float* __restrict__ b1, const float* __restrict__ b2,
    const float* __restrict__ g, const float* __restrict__ beta,
    float* __restrict__ out, int M)
{
    __shared__ __align__(16) char smem[33280];
    ushort_t* Xs = (ushort_t*)smem;            // 8 k-tiles x 1024 us = 16 KB
    ushort_t* Hs = (ushort_t*)(smem + 16384);  // [32 m][128 f] bf16 = 8 KB (swz)
    float (*epi)[260] = (float(*)[260])smem;   // 32 x 260 f32 overlay (post-loop)

    const int m0 = blockIdx.x * 32;
    const int tid = threadIdx.x;
    const int lane = tid & 63;
    const int wave = tid >> 6;
    const int l32 = lane & 31;
    const int hi  = lane >> 5;

    // ---- stage X: 8 k-tiles (proven) ----
    {
        const int lsup = (wave & 1) * 8 + (lane >> 3);
        const int clin = lane & 7;
        const int cs = clin ^ (lsup & 7);
        int r = m0 + lsup * 2 + (cs >> 2); if (r > M - 1) r = M - 1;
        const ushort_t* xp = X + (size_t)r * 256 + (cs & 3) * 8;
        ushort_t* xl = Xs + (wave & 1) * 512;
        #pragma unroll
        for (int p = 0; p < 4; ++p) {
            const int t = p * 2 + (wave >> 1);
            gl_lds16(xp + t * 32, xl + t * 1024);
        }
    }

    // ---- X fragment offsets (B-operand col / A-operand row = l32) ----
    int aOff[2];
    {
        const int sr = l32 >> 1;
        #pragma unroll
        for (int kw = 0; kw < 2; ++kw) {
            const int q = kw * 2 + hi;
            const int slot = (((l32 & 1) << 2) | q) ^ (sr & 7);
            aOff[kw] = sr * 64 + slot * 8;
        }
    }
    // ---- h-store addresses: m=l32, f = wave*32 + (i&1)*2 + (i>>1)*8 + 4*hi ----
    int hadr[8];
    #pragma unroll
    for (int i = 0; i < 8; ++i) {
        const int slin = wave * 4 + (i >> 1);
        hadr[i] = l32 * 128 + (slin ^ (l32 & 15)) * 8 + ((i & 1) + 2 * hi) * 2;
    }
    // ---- stage-2 A-frag read offsets: row m=l32, slot t*4+kw*2+hi ----
    int hOff[4][2];
    #pragma unroll
    for (int t = 0; t < 4; ++t) {
        #pragma unroll
        for (int kw = 0; kw < 2; ++kw) {
            const int slin = t * 4 + kw * 2 + hi;
            hOff[t][kw] = l32 * 128 + (slin ^ (l32 & 15)) * 8;
        }
    }

    f32x16 za0 = {}, za1 = {};
    __syncthreads();  // X staged (barrier drains vmcnt)

    for (int c = 0; c < 16; ++c) {
        // ---- stage 1: hT = w1frag(A) x xfrag(B); lane holds m=l32 column ----
        f32x16 h0 = {}, h1 = {};
        const int hcg = c * 4 + wave;
        const ushort_t* w1c = W1p + (size_t)hcg * 8192;
        #pragma unroll
        for (int t = 0; t < 8; t += 2) {
            #pragma unroll
            for (int kw = 0; kw < 2; ++kw) {
                const bf16x8 xa0 = *reinterpret_cast<const bf16x8*>(
                    Xs + t * 1024 + aOff[kw]);
                const bf16x8 xa1 = *reinterpret_cast<const bf16x8*>(
                    Xs + (t + 1) * 1024 + aOff[kw]);
                const bf16x8 wA0 = *reinterpret_cast<const bf16x8*>(
                    w1c + (t * 2 + kw) * 512 + lane * 8);
                const bf16x8 wA1 = *reinterpret_cast<const bf16x8*>(
                    w1c + ((t + 1) * 2 + kw) * 512 + lane * 8);
                h0 = __builtin_amdgcn_mfma_f32_32x32x16_bf16(wA0, xa0, h0, 0, 0, 0);
                h1 = __builtin_amdgcn_mfma_f32_32x32x16_bf16(wA1, xa1, h1, 0, 0, 0);
            }
        }

        // ---- bias + relu + pack pairs (f_loc = (r&3)+8(r>>2)+4hi) ----
        float4 bq[4];
        #pragma unroll
        for (int p = 0; p < 4; ++p)
            bq[p] = *reinterpret_cast<const float4*>(b1 + hcg * 32 + p * 8 + 4 * hi);
        int pk[8];
        #pragma unroll
        for (int i = 0; i < 8; ++i) {
            const int p = i >> 1;
            const float bv0 = (i & 1) ? bq[p].z : bq[p].x;
            const float bv1 = (i & 1) ? bq[p].w : bq[p].y;
            const float v0 = fmaxf(h0[2 * i]     + h1[2 * i]     + bv0, 0.f);
            const float v1 = fmaxf(h0[2 * i + 1] + h1[2 * i + 1] + bv1, 0.f);
            pk[i] = (int)((unsigned)f2us(v0) | ((unsigned)f2us(v1) << 16));
        }

        __syncthreads();   // prior stage-2 readers of Hs done
        #pragma unroll
        for (int i = 0; i < 8; ++i)
            *reinterpret_cast<int*>(Hs + hadr[i]) = pk[i];
        __syncthreads();   // Hs ready

        // ---- stage 2: za[nq] += h @ w2-chunk (wave owns nq0, nq0+1) ----
        const ushort_t* w2c = W2p + (size_t)c * 32768;
        const int nq0 = wave * 2;
        #pragma unroll
        for (int t = 0; t < 4; ++t) {
            #pragma unroll
            for (int kw = 0; kw < 2; ++kw) {
                const bf16x8 af = *reinterpret_cast<const bf16x8*>(Hs + hOff[t][kw]);
                const bf16x8 bf0 = *reinterpret_cast<const bf16x8*>(
                    w2c + ((nq0 * 4 + t) * 2 + kw) * 512 + lane * 8);
                const bf16x8 bf1 = *reinterpret_cast<const bf16x8*>(
                    w2c + (((nq0 + 1) * 4 + t) * 2 + kw) * 512 + lane * 8);
                za0 = __builtin_amdgcn_mfma_f32_32x32x16_bf16(af, bf0, za0, 0, 0, 0);
                za1 = __builtin_amdgcn_mfma_f32_32x32x16_bf16(af, bf1, za1, 0, 0, 0);
            }
        }
    }

    __syncthreads();  // compute done before epi overlay

    // ---- epilogue: z + b2 -> epi (all waves, disjoint cols) ----
    #pragma unroll
    for (int j = 0; j < 2; ++j) {
        const int col = wave * 64 + j * 32 + l32;
        const float bz = b2[col];
        const f32x16& zz = j ? za1 : za0;
        #pragma unroll
        for (int r = 0; r < 16; ++r)
            epi[(r & 3) + 8 * (r >> 2) + 4 * hi][col] = zz[r] + bz;
    }
    __syncthreads();

    // ---- + x resid, LN2, f32 out. 8 threads per row. ----
    const int row = tid >> 3, t8 = tid & 7;
    const int m = m0 + row;
    const int mc = (m < M) ? m : (M - 1);
    const ushort_t* xr = X + (size_t)mc * 256 + t8 * 32;
    float v[32];
    float s = 0.f, ss = 0.f;
    #pragma unroll
    for (int i = 0; i < 8; ++i) {
        const float4 e = *reinterpret_cast<const float4*>(
            &epi[row][t8 * 32 + i * 4]);
        const int2 rb = *reinterpret_cast<const int2*>(xr + i * 4);
        const float f0 = e.x + us2f((ushort_t)((unsigned)rb.x & 0xffffu));
        const float f1 = e.y + us2f((ushort_t)((unsigned)rb.x >> 16));
        const float f2 = e.z + us2f((ushort_t)((unsigned)rb.y & 0xffffu));
        const float f3 = e.w + us2f((ushort_t)((unsigned)rb.y >> 16));
        v[i * 4]     = f0; v[i * 4 + 1] = f1;
        v[i * 4 + 2] = f2; v[i * 4 + 3] = f3;
        s  += f0 + f1 + f2 + f3;
        ss += f0 * f0 + f1 * f1 + f2 * f2 + f3 * f3;
    }
    s += __shfl_xor(s, 1); ss += __shfl_xor(ss, 1);
    s += __shfl_xor(s, 2); ss += __shfl_xor(ss, 2);
    s += __shfl_xor(s, 4); ss += __shfl_xor(ss, 4);
    const float mean = s * (1.f / 256.f);
    const float var = ss * (1.f / 256.f) - mean * mean;
    const float rs = rsqrtf(var + 1e-5f);
    if (m < M) {
        #pragma unroll
        for (int i = 0; i < 8; ++i) {
            const float4 g4 = *reinterpret_cast<const float4*>(
                &g[t8 * 32 + i * 4]);
            const float4 b4 = *reinterpret_cast<const float4*>(
                &beta[t8 * 32 + i * 4]);
            float4 o4;
            o4.x = (v[i * 4]     - mean) * rs * g4.x + b4.x;
            o4.y = (v[i * 4 + 1] - mean) * rs * g4.y + b4.y;
            o4.z = (v[i * 4 + 2] - mean) * rs * g4.z + b4.z;
            o4.w = (v[i * 4 + 3] - mean) * rs * g4.w + b4.w;
            *reinterpret_cast<float4*>(
                &out[(size_t)m * 256 + t8 * 32 + i * 4]) = o4;
        }
    }
}

// ---------------------------------------------------------------------------
// MS-deformable attention v7 (unchanged — at structural gather limit).
// ---------------------------------------------------------------------------
__global__ __launch_bounds__(256) void msda_kernel_v7(
    const ushort_t* __restrict__ og,     // [M,480] bf16: offs 0..319, logits 320..479
    const float* __restrict__ refp,      // [M,10]
    const ushort_t* __restrict__ value,  // [M,256] bf16 = (B,L,H,32)
    bf16* __restrict__ out,              // [M,256] bf16
    int M, int L)
{
    const int tid = threadIdx.x;
    const int nb = gridDim.x;
    int wk = blockIdx.x;
    if ((nb & 7) == 0) {                       // bijective XCD remap
        const int per = nb >> 3;
        wk = (blockIdx.x & 7) * per + (blockIdx.x >> 3);
    }
    const int qbase = wk * 8;

    __shared__ float s_attn[8][160];   // 5120 B
    __shared__ int2  s_off[1280];      // 10240 B
    __shared__ int2  s_wh[1280];       // 10240 B -> total 25600 B

    for (int i = tid; i < 1280; i += 256) {
        int q = i / 160, j = i - q * 160;
        int qq = qbase + q;
        s_attn[q][j] = (qq < M) ? us2f(og[(size_t)qq * 480 + 320 + j]) : 0.f;
    }
    __syncthreads();

    if (tid < 64) {
        float* a = &s_attn[tid >> 3][(tid & 7) * 20];
        float mx = -1e30f;
        #pragma unroll
        for (int i = 0; i < 20; ++i) mx = fmaxf(mx, a[i]);
        float ssum = 0.f;
        #pragma unroll
        for (int i = 0; i < 20; ++i) {
            float e = __expf(a[i] - mx);
            a[i] = e;
            ssum += e;
        }
        float inv = 1.f / ssum;
        #pragma unroll
        for (int i = 0; i < 20; ++i) a[i] *= inv;
    }
    __syncthreads();

    #pragma unroll
    for (int it = 0; it < 5; ++it) {
        const int t = tid + it * 256;
        const int q  = t / 160;
        const int r  = t - q * 160;
        const int l  = (r - (r / 20) * 20) >> 2;
        const int qq = qbase + q;

        int2 offp = {0, 0};
        __half2 h01 = __floats2half2_rn(0.f, 0.f);
        __half2 h23 = h01;
        if (qq < M) {
            const int Wi = (l == 0) ? 100 : (l == 1) ? 50 : (l == 2) ? 25
                         : (l == 3) ? 13 : 7;
            const int s0 = (l == 0) ? 0 : (l == 1) ? 10000 : (l == 2) ? 12500
                         : (l == 3) ? 13125 : 13294;
            const float Wf = (float)Wi;
            const float ox = us2f(og[(size_t)qq * 480 + r * 2]);
            const float oy = us2f(og[(size_t)qq * 480 + r * 2 + 1]);
            const float2 rf = *reinterpret_cast<const float2*>(
                &refp[(size_t)qq * 10 + l * 2]);
            const float a = s_attn[q][r];

            const float px = fmaf(rf.x, Wf, -0.5f) + ox;
            const float py = fmaf(rf.y, Wf, -0.5f) + oy;
            const float x0f = floorf(px);
            const float y0f = floorf(py);
            const float lx = px - x0f;
            const float ly = py - y0f;
            const int x0 = (int)x0f;
            const int y0 = (int)y0f;

            const float wx0v = (x0 >= 0 && x0 < Wi) ? (1.f - lx) : 0.f;
            const float wx1v = (x0 + 1 >= 0 && x0 + 1 < Wi) ? lx : 0.f;
            const float wy0v = (y0 >= 0 && y0 < Wi) ? (1.f - ly) : 0.f;
            const float wy1v = (y0 + 1 >= 0 && y0 + 1 < Wi) ? ly : 0.f;

            const int c0 = min(max(x0, 0), Wi - 2);
            const int r0 = min(max(y0, 0), Wi - 2);
            const float swx0 = (x0 == c0 ? wx0v : 0.f) + (x0 + 1 == c0 ? wx1v : 0.f);
            const float swx1 = (x0 == c0 + 1 ? wx0v : 0.f) + (x0 + 1 == c0 + 1 ? wx1v : 0.f);
            const float swy0 = (y0 == r0 ? wy0v : 0.f) + (y0 + 1 == r0 ? wy1v : 0.f);
            const float swy1 = (y0 == r0 + 1 ? wy0v : 0.f) + (y0 + 1 == r0 + 1 ? wy1v : 0.f);

            offp.x = (s0 + r0 * Wi + c0) * 512;
            offp.y = offp.x + Wi * 512;
            h01 = __floats2half2_rn(a * swx0 * swy0, a * swx1 * swy0);
            h23 = __floats2half2_rn(a * swx0 * swy1, a * swx1 * swy1);
        }
        s_off[t] = offp;
        union { __half2 h; int i; } c0u, c1u;
        c0u.h = h01; c1u.h = h23;
        int2 wpk; wpk.x = c0u.i; wpk.y = c1u.i;
        s_wh[t] = wpk;
    }
    __syncthreads();

    const int qi  = tid >> 5;
    const int g   = tid & 31;
    const int h   = g >> 2;
    const int sub = g & 3;
    const int bq = qbase + qi;
    if (bq >= M) return;
    const int b = bq / L;

    const char* vb = (const char*)value + (size_t)b * L * 512 + h * 64 + sub * 16;

    float acc[8] = {};
    const int tb = qi * 160 + h * 20;
    #pragma unroll 2
    for (int p = 0; p < 20; ++p) {
        const int2 off = s_off[tb + p];
        const int2 whp = s_wh[tb + p];
        const int4 u00 = *reinterpret_cast<const int4*>(vb + off.x);
        const int4 u10 = *reinterpret_cast<const int4*>(vb + off.x + 512);
        const int4 u01 = *reinterpret_cast<const int4*>(vb + off.y);
        const int4 u11 = *reinterpret_cast<const int4*>(vb + off.y + 512);
        union { int i; __half2 h; } w0u, w1u;
        w0u.i = whp.x; w1u.i = whp.y;
        const float2 w01 = __half22float2(w0u.h);
        const float2 w23 = __half22float2(w1u.h);
        #define ACC4(u, wt)                                                        \
            acc[0] = fmaf(wt, __uint_as_float((unsigned)(u).x << 16), acc[0]);      \
            acc[1] = fmaf(wt, __uint_as_float((unsigned)(u).x & 0xffff0000u), acc[1]); \
            acc[2] = fmaf(wt, __uint_as_float((unsigned)(u).y << 16), acc[2]);      \
            acc[3] = fmaf(wt, __uint_as_float((unsigned)(u).y & 0xffff0000u), acc[3]); \
            acc[4] = fmaf(wt, __uint_as_float((unsigned)(u).z << 16), acc[4]);      \
            acc[5] = fmaf(wt, __uint_as_float((unsigned)(u).z & 0xffff0000u), acc[5]); \
            acc[6] = fmaf(wt, __uint_as_float((unsigned)(u).w << 16), acc[6]);      \
            acc[7] = fmaf(wt, __uint_as_float((unsigned)(u).w & 0xffff0000u), acc[7]);
        ACC4(u00, w01.x)
        ACC4(u10, w01.y)
        ACC4(u01, w23.x)
        ACC4(u11, w23.y)
        #undef ACC4
    }

    ushort_t o[8];
    #pragma unroll
    for (int i = 0; i < 8; ++i) o[i] = f2us(acc[i]);
    int4 pkt;
    pkt.x = (int)o[0] | ((int)o[1] << 16);
    pkt.y = (int)o[2] | ((int)o[3] << 16);
    pkt.z = (int)o[4] | ((int)o[5] << 16);
    pkt.w = (int)o[6] | ((int)o[7] << 16);
    *reinterpret_cast<int4*>((ushort_t*)out + (size_t)bq * 256 + h * 32 + sub * 8) = pkt;
}

// ---------------------------------------------------------------------------
// LayerNorm over 256, bf16 input -> bf16 out (LN1).
// ---------------------------------------------------------------------------
template<bool OUT_BF16>
__global__ __launch_bounds__(256) void ln_kernel(
    const ushort_t* __restrict__ yb, const float* __restrict__ g,
    const float* __restrict__ bta, void* __restrict__ outv, int M)
{
    const int wave = threadIdx.x >> 6, lane = threadIdx.x & 63;
    const int row = blockIdx.x * 4 + wave;
    if (row >= M) return;
    const int2 raw = *reinterpret_cast<const int2*>(&yb[(size_t)row * 256 + lane * 4]);
    float v0 = us2f((ushort_t)((unsigned)raw.x & 0xffffu));
    float v1 = us2f((ushort_t)((unsigned)raw.x >> 16));
    float v2 = us2f((ushort_t)((unsigned)raw.y & 0xffffu));
    float v3 = us2f((ushort_t)((unsigned)raw.y >> 16));
    float s  = v0 + v1 + v2 + v3;
    float ss = v0 * v0 + v1 * v1 + v2 * v2 + v3 * v3;
    #pragma unroll
    for (int o = 32; o > 0; o >>= 1) {
        s += __shfl_down(s, o);
        ss += __shfl_down(ss, o);
    }
    s = __shfl(s, 0);
    ss = __shfl(ss, 0);
    const float mean = s * (1.f / 256.f);
    const float var = ss * (1.f / 256.f) - mean * mean;
    const float rs = rsqrtf(var + 1e-5f);
    const float4 g4 = *reinterpret_cast<const float4*>(&g[lane * 4]);
    const float4 b4 = *reinterpret_cast<const float4*>(&bta[lane * 4]);
    float4 o4;
    o4.x = (v0 - mean) * rs * g4.x + b4.x;
    o4.y = (v1 - mean) * rs * g4.y + b4.y;
    o4.z = (v2 - mean) * rs * g4.z + b4.z;
    o4.w = (v3 - mean) * rs * g4.w + b4.w;
    if (OUT_BF16) {
        int2 pk;
        pk.x = (unsigned)f2us(o4.x) | ((unsigned)f2us(o4.y) << 16);
        pk.y = (unsigned)f2us(o4.z) | ((unsigned)f2us(o4.w) << 16);
        *reinterpret_cast<int2*>((ushort_t*)outv + (size_t)row * 256 + lane * 4) = pk;
    } else {
        *reinterpret_cast<float4*>((float*)outv + (size_t)row * 256 + lane * 4) = o4;
    }
}

// ---------------------------------------------------------------------------
extern "C" void kernel_launch(void* const* d_in, const int* in_sizes, int n_in,
                              void* d_out, int out_size, void* d_ws, size_t ws_size,
                              hipStream_t stream)
{
    const int B = 2, L = 13343, C = 256;
    const int M = B * L;  // 26686

    const float* src  = (const float*)d_in[0];
    const float* pos  = (const float*)d_in[1];
    const float* refp = (const float*)d_in[2];
    const float* wv   = (const float*)d_in[3];
    const float* bv   = (const float*)d_in[4];
    const float* wo   = (const float*)d_in[5];
    const float* bo   = (const float*)d_in[6];
    const float* wa   = (const float*)d_in[7];
    const float* ba   = (const float*)d_in[8];
    const float* wout = (const float*)d_in[9];
    const float* bout = (const float*)d_in[10];
    const float* ln1g = (const float*)d_in[11];
    const float* ln1b = (const float*)d_in[12];
    const float* w1   = (const float*)d_in[13];
    const float* b1   = (const float*)d_in[14];
    const float* w2   = (const float*)d_in[15];
    const float* b2   = (const float*)d_in[16];
    const float* ln2g = (const float*)d_in[17];
    const float* ln2b = (const float*)d_in[18];

    char* ws = (char*)d_ws;
    const size_t MB = 1ull << 20;
    // ---- workspace overlay ----
    bf16*  src_b  = (bf16*)(ws + 0);         // 13.7 MB
    bf16*  q_b    = (bf16*)(ws + 14 * MB);   // 13.7
    bf16*  val_b  = (bf16*)(ws + 28 * MB);   // 13.7
    bf16*  og     = (bf16*)(ws + 42 * MB);   // M*480 bf16 = 25.6 -> ends 67.6
    bf16*  acc_b  = (bf16*)(ws + 95 * MB);   // 13.7 -> ends 108.7
    bf16*  y      = (bf16*)(ws + 110 * MB);  // 13.7 bf16 (dead after LN1)
    bf16*  x_b    = (bf16*)(ws + 138 * MB);  // 13.7 (LN1 out, FFN input+resid)
    bf16* wvt    = (bf16*)(ws + 152 * MB);   // 256*256
    bf16* wcat   = wvt + 256 * 256;          // 480*256
    bf16* woutt  = wcat + 480 * 256;         // 256*256
    ushort_t* w1p = (ushort_t*)(woutt + 256 * 256);  // packed, 2048*256
    ushort_t* w2p = w1p + 2048 * 256;                // packed, 256*2048
    float* bcat  = (float*)(w2p + 256 * 2048);       // 480 f32
    (void)ws_size; (void)n_in; (void)in_sizes; (void)out_size;

    const int mt64  = (M + 63) / 64;        // 417
    const int gm8   = (mt64 + 7) / 8;       // 53
    const int mt128 = (M + 127) / 128;      // 209
    const int gb8   = (mt128 + 7) / 8;      // 27
    const int mt32  = (M + 31) / 32;        // 834
    const int lnb   = (M + 3) / 4;          // 6672

    // ---- fused weight prep (one launch; w1/w2 packed fragment-major) ----
    prep_kernel<<<1274, 256, 0, stream>>>(wv, wo, wa, wout, w1, w2, bo, ba,
                                          wvt, wcat, woutt, w1p, w2p, bcat);

    // ---- fused activation casts (float4) ----
    cast2_kernel<<<(M * C / 4 + 255) / 256, 256, 0, stream>>>(
        src, pos, src_b, q_b, M * C);

    // value = src @ wv + bv  (bf16)  [small kernel, NT=2]
    gemm_mfma_s<false, true, false, false, 2, 4><<<gm8 * 16, 256, 0, stream>>>(
        (const ushort_t*)src_b, (const ushort_t*)wvt, bv, nullptr, val_b,
        M, 256, 256, mt64);

    // og = q @ [wo|wa] + [bo|ba]  (bf16, N=480)  [BIG kernel, NT=4]
    gemm_mfma_b<false, true, false, false, 4><<<gb8 * 32, 256, 0, stream>>>(
        (const ushort_t*)q_b, (const ushort_t*)wcat, bcat, nullptr, og,
        M, 480, 256, mt128);

    // deformable attention -> acc_b (bf16)  [batch->XCD remap]
    msda_kernel_v7<<<(M + 7) / 8, 256, 0, stream>>>(
        (const ushort_t*)og, refp, (const ushort_t*)val_b, acc_b, M, L);

    // y = acc @ wout + bout + src  (bf16 out, f32 resid)  [small kernel, NT=2]
    gemm_mfma_s<false, true, true, false, 2, 4><<<gm8 * 16, 256, 0, stream>>>(
        (const ushort_t*)acc_b, (const ushort_t*)woutt, bout, src, y,
        M, 256, 256, mt64);

    // x_b = LN1(y)  (bf16 in, bf16 out)
    ln_kernel<true><<<lnb, 256, 0, stream>>>(
        (const ushort_t*)y, ln1g, ln1b, x_b, M);

    // out = LN2( x + relu(x@w1+b1)@w2 + b2 )  — FUSED v4 (swz u32 h-store)
    ffn_fused4<<<mt32, 256, 0, stream>>>(
        (const ushort_t*)x_b, w1p, w2p, b1, b2, ln2g, ln2b,
        (float*)d_out, M);
}

// Round 12
// 355.471 us; speedup vs baseline: 1.3110x; 1.0041x over previous
//
#include <hip/hip_runtime.h>
#include <hip/hip_bf16.h>
#include <hip/hip_fp16.h>

typedef __hip_bfloat16 bf16;
typedef unsigned short ushort_t;
typedef __attribute__((ext_vector_type(8))) short bf16x8;
typedef __attribute__((ext_vector_type(16))) float f32x16;

__device__ __forceinline__ float us2f(unsigned short u) {
    unsigned int x = ((unsigned int)u) << 16;
    return __uint_as_float(x);
}
__device__ __forceinline__ ushort_t f2us(float f) {
    return ((__hip_bfloat16_raw)__float2bfloat16(f)).x;
}

// async global->LDS, 16 B per lane. LDS dest = wave-uniform base + lane*16.
__device__ __forceinline__ void gl_lds16(const ushort_t* g, ushort_t* l) {
    __builtin_amdgcn_global_load_lds(
        (const __attribute__((address_space(1))) void*)g,
        (__attribute__((address_space(3))) void*)l, 16, 0, 0);
}

// ---------------------------------------------------------------------------
// Fused input cast (float4): src_b = bf16(src), q_b = bf16(src + pos)
// ---------------------------------------------------------------------------
__global__ __launch_bounds__(256) void cast2_kernel(
    const float* __restrict__ src, const float* __restrict__ pos,
    bf16* __restrict__ src_b, bf16* __restrict__ q_b, int n)
{
    int i = (blockIdx.x * 256 + threadIdx.x) * 4;
    if (i < n) {
        const float4 s4 = *reinterpret_cast<const float4*>(&src[i]);
        const float4 p4 = *reinterpret_cast<const float4*>(&pos[i]);
        int2 sp, qp;
        sp.x = (unsigned)f2us(s4.x) | ((unsigned)f2us(s4.y) << 16);
        sp.y = (unsigned)f2us(s4.z) | ((unsigned)f2us(s4.w) << 16);
        qp.x = (unsigned)f2us(s4.x + p4.x) | ((unsigned)f2us(s4.y + p4.y) << 16);
        qp.y = (unsigned)f2us(s4.z + p4.z) | ((unsigned)f2us(s4.w + p4.w) << 16);
        *reinterpret_cast<int2*>((ushort_t*)src_b + i) = sp;
        *reinterpret_cast<int2*>((ushort_t*)q_b + i) = qp;
    }
}

// ---------------------------------------------------------------------------
// Fused weight prep. Small weights (wv, wo|wa): transpose-cast to [N][K] bf16.
// wout/w1/w2: packed FRAGMENT-MAJOR:
//   mode-1 fragment (ng,t,kw,lane): 16 B = W[k=t*32+kw*16+(l>>5)*8+e][n=ng*32+(l&31)]
//        at ushort ((ng*8+t)*2+kw)*512 + lane*8   (wout: ng 0..7; w1: ng 0..63)
//   w2p  fragment (c,nq,t,kw,lane): w2[f=c*128+t*32+kw*16+(l>>5)*8+e][n=nq*32+(l&31)]
//        at ushort (((c*8+nq)*4+t)*2+kw)*512 + lane*8
// ---------------------------------------------------------------------------
__global__ __launch_bounds__(256) void prep_kernel(
    const float* __restrict__ wv, const float* __restrict__ wo,
    const float* __restrict__ wa, const float* __restrict__ wout,
    const float* __restrict__ w1, const float* __restrict__ w2,
    const float* __restrict__ bo, const float* __restrict__ ba,
    bf16* __restrict__ wvt, bf16* __restrict__ wcat,
    ushort_t* __restrict__ woutp,
    ushort_t* __restrict__ w1p, ushort_t* __restrict__ w2p,
    float* __restrict__ bcat)
{
    __shared__ float tile[32][33];
    const int b = blockIdx.x;
    const float* W; bf16* Wt = nullptr; ushort_t* Wp = nullptr;
    int K, N, tb, mode = 0;
    if (b < 64)        { W = wv;   Wt = wvt;            K = 256;  N = 256;  tb = b; }
    else if (b < 144)  { W = wo;   Wt = wcat;           K = 256;  N = 320;  tb = b - 64; }
    else if (b < 184)  { W = wa;   Wt = wcat + 320*256; K = 256;  N = 160;  tb = b - 144; }
    else if (b < 248)  { W = wout; Wp = woutp; mode = 1; K = 256; N = 256;  tb = b - 184; }
    else if (b < 760)  { W = w1;   Wp = w1p; mode = 1;  K = 256;  N = 2048; tb = b - 248; }
    else if (b < 1272) { W = w2;   Wp = w2p; mode = 2;  K = 2048; N = 256;  tb = b - 760; }
    else {
        int i = (b - 1272) * 256 + threadIdx.x;
        if (i < 320) bcat[i] = bo[i];
        else if (i < 480) bcat[i] = ba[i - 320];
        return;
    }
    const int ntn = N >> 5;
    const int nb = (tb % ntn) * 32, kb = (tb / ntn) * 32;
    const int tx = threadIdx.x & 31, ty = threadIdx.x >> 5;  // 32 x 8
    #pragma unroll
    for (int i = 0; i < 32; i += 8) {
        int k = kb + ty + i, n = nb + tx;
        tile[ty + i][tx] = (k < K && n < N) ? W[(size_t)k * N + n] : 0.f;
    }
    __syncthreads();
    if (mode == 0) {
        #pragma unroll
        for (int i = 0; i < 32; i += 8) {
            int n = nb + ty + i, k = kb + tx;
            if (n < N && k < K)
                Wt[(size_t)n * K + k] = __float2bfloat16(tile[tx][ty + i]);
        }
    } else if (threadIdx.x < 128) {
        const int l = threadIdx.x & 63, kw = threadIdx.x >> 6;
        const int kb8 = kw * 16 + (l >> 5) * 8;
        const int nx = l & 31;
        ushort_t tmp[8];
        #pragma unroll
        for (int e = 0; e < 8; ++e) tmp[e] = f2us(tile[kb8 + e][nx]);
        size_t base;
        if (mode == 1)
            base = ((size_t)(((nb >> 5) * 8 + (kb >> 5)) * 2 + kw)) * 512;
        else
            base = ((size_t)((((kb >> 7) * 8 + (nb >> 5)) * 4 + ((kb >> 5) & 3)) * 2 + kw)) * 512;
        *reinterpret_cast<int4*>(Wp + base + l * 8) =
            *reinterpret_cast<const int4*>(tmp);
    }
}

// ---------------------------------------------------------------------------
// MFMA bf16 GEMM (64x128 tile, M-split), swizzled-LDS, double-buffered.
// (proven R5/R6 kernel — used for the value GEMM)
// ---------------------------------------------------------------------------
template<bool RELU, bool OUT_BF16, bool HAS_RESID, bool RESID_BF16, int NT, int WPE>
__global__ __launch_bounds__(256, WPE) void gemm_mfma_s(
    const ushort_t* __restrict__ A,    // [M][K] bf16
    const ushort_t* __restrict__ Bt,   // [N][K] bf16
    const float* __restrict__ bias,    // [N] f32
    const void* __restrict__ residv,   // [M][N] f32 or bf16
    void* __restrict__ outv, int M, int N, int K, int mtiles)
{
    __shared__ __align__(16) char smemraw[24576];
    ushort_t* Asmem = (ushort_t*)smemraw;
    ushort_t* Bsmem = (ushort_t*)(smemraw + 4096);
    float (*epi)[68] = (float(*)[68])smemraw;

    const int lid = blockIdx.x;
    const int tbk = lid >> 3;
    const int xb = tbk & (NT - 1);
    const int yg = (tbk / NT) * 8 + (lid & 7);
    if (yg >= mtiles) return;
    const int m0 = yg * 64;
    const int n0 = xb * 128;

    const int tid = threadIdx.x;
    const int lane = tid & 63;
    const int wave = tid >> 6;
    const int l32 = lane & 31;
    const int hi  = lane >> 5;
    const int wm = wave >> 1;
    const int wn = wave & 1;

    const int lsup = lane >> 3;
    const int clin = lane & 7;

    const int gsA = wave * 8 + lsup;
    const int csA = clin ^ (gsA & 7);
    int rA = m0 + gsA * 2 + (csA >> 2); if (rA > M - 1) rA = M - 1;
    const ushort_t* aP = A + (size_t)rA * K + (csA & 3) * 8;
    ushort_t* aL = Asmem + wave * 512;

    const ushort_t* bP[2]; ushort_t* bL[2];
    #pragma unroll
    for (int i = 0; i < 2; ++i) {
        const int gsB = wave * 16 + i * 8 + lsup;
        const int csB = clin ^ (gsB & 7);
        int rB = n0 + gsB * 2 + (csB >> 2); if (rB > N - 1) rB = N - 1;
        bP[i] = Bt + (size_t)rB * K + (csB & 3) * 8;
        bL[i] = Bsmem + (wave * 16 + i * 8) * 64;
    }

    const int arow = wm * 32 + l32;
    const int asup = arow >> 1;
    const ushort_t* aR[2];
    #pragma unroll
    for (int kw = 0; kw < 2; ++kw) {
        const int q = kw * 2 + hi;
        const int slot = (((arow & 1) << 2) | q) ^ (asup & 7);
        aR[kw] = Asmem + asup * 64 + slot * 8;
    }
    const ushort_t* bR[2][2];
    #pragma unroll
    for (int j = 0; j < 2; ++j) {
        const int brow = wn * 64 + j * 32 + l32;
        const int bsup = brow >> 1;
        #pragma unroll
        for (int kw = 0; kw < 2; ++kw) {
            const int q = kw * 2 + hi;
            const int slot = (((brow & 1) << 2) | q) ^ (bsup & 7);
            bR[j][kw] = Bsmem + bsup * 64 + slot * 8;
        }
    }

    f32x16 acc[2] = {};

    auto stage = [&](int ofs) {
        gl_lds16(aP, aL + ofs);             aP    += 32;
        gl_lds16(bP[0], bL[0] + ofs);       bP[0] += 32;
        gl_lds16(bP[1], bL[1] + ofs);       bP[1] += 32;
    };
    auto compute = [&](int ofs) {
        #pragma unroll
        for (int kw = 0; kw < 2; ++kw) {
            const bf16x8 af = *reinterpret_cast<const bf16x8*>(aR[kw] + ofs);
            #pragma unroll
            for (int j = 0; j < 2; ++j)
                acc[j] = __builtin_amdgcn_mfma_f32_32x32x16_bf16(
                    af, *reinterpret_cast<const bf16x8*>(bR[j][kw] + ofs),
                    acc[j], 0, 0, 0);
        }
    };

    const int ntile = K >> 5;
    stage(0);
    for (int t = 0; t < ntile; t += 2) {
        __syncthreads();
        stage(6144);
        compute(0);
        __syncthreads();
        if (t + 2 < ntile) stage(0);
        compute(6144);
    }
    __syncthreads();

    #pragma unroll
    for (int half = 0; half < 2; ++half) {
        if (wn == half) {
            #pragma unroll
            for (int j = 0; j < 2; ++j) {
                const int coll = j * 32 + l32;
                const int n = n0 + half * 64 + coll;
                const float bv = (n < N) ? bias[n] : 0.f;
                #pragma unroll
                for (int r = 0; r < 16; ++r) {
                    const int row = wm * 32 + hi * 4 + (r & 3) + (r >> 2) * 8;
                    epi[row][coll] = acc[j][r] + bv;
                }
            }
        }
        __syncthreads();
        #pragma unroll
        for (int i = 0; i < 4; ++i) {
            const int idx = i * 256 + tid;
            const int row = idx >> 4;
            const int c4  = idx & 15;
            const int m = m0 + row;
            const int n = n0 + half * 64 + c4 * 4;
            if (m < M && n + 3 < N) {
                float4 v = *reinterpret_cast<const float4*>(&epi[row][c4 * 4]);
                if (HAS_RESID) {
                    if (RESID_BF16) {
                        const int2 rw = *reinterpret_cast<const int2*>(
                            (const ushort_t*)residv + (size_t)m * N + n);
                        v.x += us2f((ushort_t)((unsigned)rw.x & 0xffffu));
                        v.y += us2f((ushort_t)((unsigned)rw.x >> 16));
                        v.z += us2f((ushort_t)((unsigned)rw.y & 0xffffu));
                        v.w += us2f((ushort_t)((unsigned)rw.y >> 16));
                    } else {
                        const float4 r4 = *reinterpret_cast<const float4*>(
                            (const float*)residv + (size_t)m * N + n);
                        v.x += r4.x; v.y += r4.y; v.z += r4.z; v.w += r4.w;
                    }
                }
                if (RELU) {
                    v.x = fmaxf(v.x, 0.f); v.y = fmaxf(v.y, 0.f);
                    v.z = fmaxf(v.z, 0.f); v.w = fmaxf(v.w, 0.f);
                }
                if (OUT_BF16) {
                    int2 pk;
                    pk.x = (unsigned)f2us(v.x) | ((unsigned)f2us(v.y) << 16);
                    pk.y = (unsigned)f2us(v.z) | ((unsigned)f2us(v.w) << 16);
                    *reinterpret_cast<int2*>((ushort_t*)outv + (size_t)m * N + n) = pk;
                } else {
                    *reinterpret_cast<float4*>((float*)outv + (size_t)m * N + n) = v;
                }
            }
        }
        if (half == 0) __syncthreads();
    }
}

// ---------------------------------------------------------------------------
// BIG MFMA bf16 GEMM: 128x128 tile (proven R7 kernel — used for og, N=480).
// ---------------------------------------------------------------------------
template<bool RELU, bool OUT_BF16, bool HAS_RESID, bool RESID_BF16, int NT>
__global__ __launch_bounds__(256, 4) void gemm_mfma_b(
    const ushort_t* __restrict__ A,    // [M][K] bf16
    const ushort_t* __restrict__ Bt,   // [N][K] bf16
    const float* __restrict__ bias,    // [N] f32
    const void* __restrict__ residv,   // [M][N] f32 or bf16
    void* __restrict__ outv, int M, int N, int K, int mtiles)
{
    __shared__ __align__(16) char smemraw[32768];
    ushort_t* Asmem = (ushort_t*)smemraw;
    ushort_t* Bsmem = (ushort_t*)(smemraw + 8192);
    float (*epi)[68] = (float(*)[68])smemraw;

    const int lid = blockIdx.x;
    const int tbk = lid >> 3;
    const int xb = tbk & (NT - 1);
    const int yg = (tbk / NT) * 8 + (lid & 7);
    if (yg >= mtiles) return;
    const int m0 = yg * 128;
    const int n0 = xb * 128;

    const int tid = threadIdx.x;
    const int lane = tid & 63;
    const int wave = tid >> 6;
    const int l32 = lane & 31;
    const int hi  = lane >> 5;
    const int wm = wave >> 1;
    const int wn = wave & 1;

    const int lsup = lane >> 3;
    const int clin = lane & 7;
    const ushort_t *aP[2], *bP[2];
    ushort_t *aL[2], *bL[2];
    #pragma unroll
    for (int i = 0; i < 2; ++i) {
        const int gs = wave * 16 + i * 8 + lsup;
        const int cs = clin ^ (gs & 7);
        int rA = m0 + gs * 2 + (cs >> 2); if (rA > M - 1) rA = M - 1;
        aP[i] = A + (size_t)rA * K + (cs & 3) * 8;
        aL[i] = Asmem + (wave * 16 + i * 8) * 64;
        int rB = n0 + gs * 2 + (cs >> 2); if (rB > N - 1) rB = N - 1;
        bP[i] = Bt + (size_t)rB * K + (cs & 3) * 8;
        bL[i] = Bsmem + (wave * 16 + i * 8) * 64;
    }

    const ushort_t* aR[2][2];
    const ushort_t* bR[2][2];
    #pragma unroll
    for (int mi = 0; mi < 2; ++mi) {
        const int arow = wm * 64 + mi * 32 + l32;
        const int asup = arow >> 1;
        #pragma unroll
        for (int kw = 0; kw < 2; ++kw) {
            const int q = kw * 2 + hi;
            const int slot = (((arow & 1) << 2) | q) ^ (asup & 7);
            aR[mi][kw] = Asmem + asup * 64 + slot * 8;
        }
    }
    #pragma unroll
    for (int ni = 0; ni < 2; ++ni) {
        const int brow = wn * 64 + ni * 32 + l32;
        const int bsup = brow >> 1;
        #pragma unroll
        for (int kw = 0; kw < 2; ++kw) {
            const int q = kw * 2 + hi;
            const int slot = (((brow & 1) << 2) | q) ^ (bsup & 7);
            bR[ni][kw] = Bsmem + bsup * 64 + slot * 8;
        }
    }

    f32x16 a00 = {}, a01 = {}, a10 = {}, a11 = {};

    auto stage = [&](int ofs) {
        gl_lds16(aP[0], aL[0] + ofs); aP[0] += 32;
        gl_lds16(aP[1], aL[1] + ofs); aP[1] += 32;
        gl_lds16(bP[0], bL[0] + ofs); bP[0] += 32;
        gl_lds16(bP[1], bL[1] + ofs); bP[1] += 32;
    };
    auto compute = [&](int ofs) {
        #pragma unroll
        for (int kw = 0; kw < 2; ++kw) {
            const bf16x8 af0 = *reinterpret_cast<const bf16x8*>(aR[0][kw] + ofs);
            const bf16x8 af1 = *reinterpret_cast<const bf16x8*>(aR[1][kw] + ofs);
            const bf16x8 bf0 = *reinterpret_cast<const bf16x8*>(bR[0][kw] + ofs);
            const bf16x8 bf1 = *reinterpret_cast<const bf16x8*>(bR[1][kw] + ofs);
            a00 = __builtin_amdgcn_mfma_f32_32x32x16_bf16(af0, bf0, a00, 0, 0, 0);
            a01 = __builtin_amdgcn_mfma_f32_32x32x16_bf16(af0, bf1, a01, 0, 0, 0);
            a10 = __builtin_amdgcn_mfma_f32_32x32x16_bf16(af1, bf0, a10, 0, 0, 0);
            a11 = __builtin_amdgcn_mfma_f32_32x32x16_bf16(af1, bf1, a11, 0, 0, 0);
        }
    };

    const int ntile = K >> 5;
    stage(0);
    for (int t = 0; t < ntile; t += 2) {
        __syncthreads();
        stage(8192);
        compute(0);
        __syncthreads();
        if (t + 2 < ntile) stage(0);
        compute(8192);
    }
    __syncthreads();

    #pragma unroll
    for (int qd = 0; qd < 4; ++qd) {
        const int rh = qd >> 1, ch = qd & 1;
        if (qd) __syncthreads();
        if (wm == rh && wn == ch) {
            #pragma unroll
            for (int ni = 0; ni < 2; ++ni) {
                const int col = ni * 32 + l32;
                const int n = n0 + ch * 64 + col;
                const float bv = (n < N) ? bias[n] : 0.f;
                #pragma unroll
                for (int mi = 0; mi < 2; ++mi) {
                    const f32x16& ac = (mi == 0) ? (ni == 0 ? a00 : a01)
                                                 : (ni == 0 ? a10 : a11);
                    #pragma unroll
                    for (int r = 0; r < 16; ++r) {
                        const int row = mi * 32 + hi * 4 + (r & 3) + (r >> 2) * 8;
                        epi[row][col] = ac[r] + bv;
                    }
                }
            }
        }
        __syncthreads();
        #pragma unroll
        for (int i = 0; i < 4; ++i) {
            const int idx = i * 256 + tid;
            const int row = idx >> 4;
            const int c4  = idx & 15;
            const int m = m0 + rh * 64 + row;
            const int n = n0 + ch * 64 + c4 * 4;
            if (m < M && n + 3 < N) {
                float4 v = *reinterpret_cast<const float4*>(&epi[row][c4 * 4]);
                if (HAS_RESID) {
                    if (RESID_BF16) {
                        const int2 rw = *reinterpret_cast<const int2*>(
                            (const ushort_t*)residv + (size_t)m * N + n);
                        v.x += us2f((ushort_t)((unsigned)rw.x & 0xffffu));
                        v.y += us2f((ushort_t)((unsigned)rw.x >> 16));
                        v.z += us2f((ushort_t)((unsigned)rw.y & 0xffffu));
                        v.w += us2f((ushort_t)((unsigned)rw.y >> 16));
                    } else {
                        const float4 r4 = *reinterpret_cast<const float4*>(
                            (const float*)residv + (size_t)m * N + n);
                        v.x += r4.x; v.y += r4.y; v.z += r4.z; v.w += r4.w;
                    }
                }
                if (RELU) {
                    v.x = fmaxf(v.x, 0.f); v.y = fmaxf(v.y, 0.f);
                    v.z = fmaxf(v.z, 0.f); v.w = fmaxf(v.w, 0.f);
                }
                if (OUT_BF16) {
                    int2 pk;
                    pk.x = (unsigned)f2us(v.x) | ((unsigned)f2us(v.y) << 16);
                    pk.y = (unsigned)f2us(v.z) | ((unsigned)f2us(v.w) << 16);
                    *reinterpret_cast<int2*>((ushort_t*)outv + (size_t)m * N + n) = pk;
                } else {
                    *reinterpret_cast<float4*>((float*)outv + (size_t)m * N + n) = v;
                }
            }
        }
    }
}

// ---------------------------------------------------------------------------
// FUSED wout-GEMM + LN1: x_b = LN1( acc @ wout + bout + src ).
// Built from the twice-verified ffn_fused pieces: 32-row block, A = acc tile
// via swizzled gl_lds16 staging, B = packed wout fragments (mode-1, nq 0..7),
// per-wave za0/za1 over its 2 col-groups, then epi[32][260] repack + f32
// src-resid + LN -> bf16 out.  y never touches HBM (saves 27 MB + 1 launch).
// LDS 33280 B, ~4 blocks/CU.
// ---------------------------------------------------------------------------
__global__ __launch_bounds__(256, 4) void woutln_kernel(
    const ushort_t* __restrict__ A,    // acc_b [M][256] bf16
    const ushort_t* __restrict__ Wp,   // packed wout, 128 KB
    const float* __restrict__ bias,    // bout
    const float* __restrict__ resid,   // src f32 [M][256]
    const float* __restrict__ g, const float* __restrict__ beta,
    bf16* __restrict__ out, int M)     // x_b
{
    __shared__ __align__(16) char smem[33280];
    ushort_t* Xs = (ushort_t*)smem;            // 8 k-tiles x 1024 us = 16 KB
    float (*epi)[260] = (float(*)[260])smem;   // 32 x 260 f32 overlay

    const int m0 = blockIdx.x * 32;
    const int tid = threadIdx.x;
    const int lane = tid & 63;
    const int wave = tid >> 6;
    const int l32 = lane & 31;
    const int hi  = lane >> 5;

    // ---- stage acc tile: 8 k-tiles (proven pattern) ----
    {
        const int lsup = (wave & 1) * 8 + (lane >> 3);
        const int clin = lane & 7;
        const int cs = clin ^ (lsup & 7);
        int r = m0 + lsup * 2 + (cs >> 2); if (r > M - 1) r = M - 1;
        const ushort_t* xp = A + (size_t)r * 256 + (cs & 3) * 8;
        ushort_t* xl = Xs + (wave & 1) * 512;
        #pragma unroll
        for (int p = 0; p < 4; ++p) {
            const int t = p * 2 + (wave >> 1);
            gl_lds16(xp + t * 32, xl + t * 1024);
        }
    }

    // ---- A-fragment offsets (row = l32) ----
    int aOff[2];
    {
        const int sr = l32 >> 1;
        #pragma unroll
        for (int kw = 0; kw < 2; ++kw) {
            const int q = kw * 2 + hi;
            const int slot = (((l32 & 1) << 2) | q) ^ (sr & 7);
            aOff[kw] = sr * 64 + slot * 8;
        }
    }

    f32x16 za0 = {}, za1 = {};
    __syncthreads();  // acc staged (barrier drains vmcnt)

    const int nq0 = wave * 2;
    #pragma unroll
    for (int t = 0; t < 8; ++t) {
        #pragma unroll
        for (int kw = 0; kw < 2; ++kw) {
            const bf16x8 af = *reinterpret_cast<const bf16x8*>(
                Xs + t * 1024 + aOff[kw]);
            const bf16x8 b0 = *reinterpret_cast<const bf16x8*>(
                Wp + ((nq0 * 8 + t) * 2 + kw) * 512 + lane * 8);
            const bf16x8 b1 = *reinterpret_cast<const bf16x8*>(
                Wp + (((nq0 + 1) * 8 + t) * 2 + kw) * 512 + lane * 8);
            za0 = __builtin_amdgcn_mfma_f32_32x32x16_bf16(af, b0, za0, 0, 0, 0);
            za1 = __builtin_amdgcn_mfma_f32_32x32x16_bf16(af, b1, za1, 0, 0, 0);
        }
    }

    __syncthreads();  // Xs dead; epi overlay begins

    // ---- z + bout -> epi (all waves, disjoint cols) ----
    #pragma unroll
    for (int j = 0; j < 2; ++j) {
        const int col = wave * 64 + j * 32 + l32;
        const float bz = bias[col];
        const f32x16& zz = j ? za1 : za0;
        #pragma unroll
        for (int r = 0; r < 16; ++r)
            epi[(r & 3) + 8 * (r >> 2) + 4 * hi][col] = zz[r] + bz;
    }
    __syncthreads();

    // ---- + src resid (f32), LN1, bf16 out. 8 threads per row. ----
    const int row = tid >> 3, t8 = tid & 7;
    const int m = m0 + row;
    const int mc = (m < M) ? m : (M - 1);
    const float* xr = resid + (size_t)mc * 256 + t8 * 32;
    float v[32];
    float s = 0.f, ss = 0.f;
    #pragma unroll
    for (int i = 0; i < 8; ++i) {
        const float4 e = *reinterpret_cast<const float4*>(
            &epi[row][t8 * 32 + i * 4]);
        const float4 r4 = *reinterpret_cast<const float4*>(xr + i * 4);
        const float f0 = e.x + r4.x;
        const float f1 = e.y + r4.y;
        const float f2 = e.z + r4.z;
        const float f3 = e.w + r4.w;
        v[i * 4]     = f0; v[i * 4 + 1] = f1;
        v[i * 4 + 2] = f2; v[i * 4 + 3] = f3;
        s  += f0 + f1 + f2 + f3;
        ss += f0 * f0 + f1 * f1 + f2 * f2 + f3 * f3;
    }
    s += __shfl_xor(s, 1); ss += __shfl_xor(ss, 1);
    s += __shfl_xor(s, 2); ss += __shfl_xor(ss, 2);
    s += __shfl_xor(s, 4); ss += __shfl_xor(ss, 4);
    const float mean = s * (1.f / 256.f);
    const float var = ss * (1.f / 256.f) - mean * mean;
    const float rs = rsqrtf(var + 1e-5f);
    if (m < M) {
        #pragma unroll
        for (int i = 0; i < 8; ++i) {
            const float4 g4 = *reinterpret_cast<const float4*>(
                &g[t8 * 32 + i * 4]);
            const float4 b4 = *reinterpret_cast<const float4*>(
                &beta[t8 * 32 + i * 4]);
            float4 o4;
            o4.x = (v[i * 4]     - mean) * rs * g4.x + b4.x;
            o4.y = (v[i * 4 + 1] - mean) * rs * g4.y + b4.y;
            o4.z = (v[i * 4 + 2] - mean) * rs * g4.z + b4.z;
            o4.w = (v[i * 4 + 3] - mean) * rs * g4.w + b4.w;
            int2 pk;
            pk.x = (unsigned)f2us(o4.x) | ((unsigned)f2us(o4.y) << 16);
            pk.y = (unsigned)f2us(o4.z) | ((unsigned)f2us(o4.w) << 16);
            *reinterpret_cast<int2*>(
                (ushort_t*)out + (size_t)m * 256 + t8 * 32 + i * 4) = pk;
        }
    }
}

// ---------------------------------------------------------------------------
// FUSED FFN v2 (R9-verified, best-measured 112 µs): out = LN2( x +
// relu(x@w1+b1)@w2 + b2 ).  h never hits HBM.
// ---------------------------------------------------------------------------
__global__ __launch_bounds__(256, 3) void ffn_fused2(
    const ushort_t* __restrict__ X,    // [M][256] bf16 (post-LN1 x_b)
    const ushort_t* __restrict__ W1p,  // packed, 1 MB
    const ushort_t* __restrict__ W2p,  // packed, 1 MB
    const float* __restrict__ b1, const float* __restrict__ b2,
    const float* __restrict__ g, const float* __restrict__ beta,
    float* __restrict__ out, int M)
{
    __shared__ __align__(16) char smem[33280];
    ushort_t* Xs = (ushort_t*)smem;            // 8 k-tiles x 1024 us = 16 KB
    ushort_t* Hs = (ushort_t*)(smem + 16384);  // 4 k-tiles x 1024 us = 8 KB
    float (*epi)[260] = (float(*)[260])smem;   // 32 x 260 f32 overlay

    const int m0 = blockIdx.x * 32;
    const int tid = threadIdx.x;
    const int lane = tid & 63;
    const int wave = tid >> 6;
    const int l32 = lane & 31;
    const int hi  = lane >> 5;

    // ---- stage X: 8 k-tiles ----
    {
        const int lsup = (wave & 1) * 8 + (lane >> 3);
        const int clin = lane & 7;
        const int cs = clin ^ (lsup & 7);
        int r = m0 + lsup * 2 + (cs >> 2); if (r > M - 1) r = M - 1;
        const ushort_t* xp = X + (size_t)r * 256 + (cs & 3) * 8;
        ushort_t* xl = Xs + (wave & 1) * 512;
        #pragma unroll
        for (int p = 0; p < 4; ++p) {
            const int t = p * 2 + (wave >> 1);
            gl_lds16(xp + t * 32, xl + t * 1024);
        }
    }

    int aOff[2];
    {
        const int sr = l32 >> 1;
        #pragma unroll
        for (int kw = 0; kw < 2; ++kw) {
            const int q = kw * 2 + hi;
            const int slot = (((l32 & 1) << 2) | q) ^ (sr & 7);
            aOff[kw] = sr * 64 + slot * 8;
        }
    }
    int hadr[16];
    #pragma unroll
    for (int r = 0; r < 16; ++r) {
        const int m = (r & 3) + 8 * (r >> 2) + 4 * hi;
        const int slot = (((m & 1) << 2) | (l32 >> 3)) ^ ((m >> 1) & 7);
        hadr[r] = wave * 1024 + (m >> 1) * 64 + slot * 8 + (l32 & 7);
    }

    f32x16 za0 = {}, za1 = {};
    __syncthreads();

    for (int c = 0; c < 16; ++c) {
        f32x16 h0 = {}, h1 = {};
        const int hcg = c * 4 + wave;
        const ushort_t* w1c = W1p + (size_t)hcg * 8192;
        #pragma unroll
        for (int t = 0; t < 8; t += 2) {
            #pragma unroll
            for (int kw = 0; kw < 2; ++kw) {
                const bf16x8 a0 = *reinterpret_cast<const bf16x8*>(
                    Xs + t * 1024 + aOff[kw]);
                const bf16x8 a1 = *reinterpret_cast<const bf16x8*>(
                    Xs + (t + 1) * 1024 + aOff[kw]);
                const bf16x8 b0 = *reinterpret_cast<const bf16x8*>(
                    w1c + (t * 2 + kw) * 512 + lane * 8);
                const bf16x8 b1f = *reinterpret_cast<const bf16x8*>(
                    w1c + ((t + 1) * 2 + kw) * 512 + lane * 8);
                h0 = __builtin_amdgcn_mfma_f32_32x32x16_bf16(a0, b0, h0, 0, 0, 0);
                h1 = __builtin_amdgcn_mfma_f32_32x32x16_bf16(a1, b1f, h1, 0, 0, 0);
            }
        }
        const float bb = b1[hcg * 32 + l32];

        __syncthreads();
        #pragma unroll
        for (int r = 0; r < 16; ++r)
            Hs[hadr[r]] = f2us(fmaxf(h0[r] + h1[r] + bb, 0.f));
        __syncthreads();

        const ushort_t* w2c = W2p + (size_t)c * 32768;
        const int nq0 = wave * 2;
        #pragma unroll
        for (int t = 0; t < 4; ++t) {
            #pragma unroll
            for (int kw = 0; kw < 2; ++kw) {
                const bf16x8 af = *reinterpret_cast<const bf16x8*>(
                    Hs + t * 1024 + aOff[kw]);
                const bf16x8 bf0 = *reinterpret_cast<const bf16x8*>(
                    w2c + ((nq0 * 4 + t) * 2 + kw) * 512 + lane * 8);
                const bf16x8 bf1 = *reinterpret_cast<const bf16x8*>(
                    w2c + (((nq0 + 1) * 4 + t) * 2 + kw) * 512 + lane * 8);
                za0 = __builtin_amdgcn_mfma_f32_32x32x16_bf16(af, bf0, za0, 0, 0, 0);
                za1 = __builtin_amdgcn_mfma_f32_32x32x16_bf16(af, bf1, za1, 0, 0, 0);
            }
        }
    }

    __syncthreads();

    #pragma unroll
    for (int j = 0; j < 2; ++j) {
        const int col = wave * 64 + j * 32 + l32;
        const float bz = b2[col];
        const f32x16& zz = j ? za1 : za0;
        #pragma unroll
        for (int r = 0; r < 16; ++r)
            epi[(r & 3) + 8 * (r >> 2) + 4 * hi][col] = zz[r] + bz;
    }
    __syncthreads();

    const int row = tid >> 3, t8 = tid & 7;
    const int m = m0 + row;
    const int mc = (m < M) ? m : (M - 1);
    const ushort_t* xr = X + (size_t)mc * 256 + t8 * 32;
    float v[32];
    float s = 0.f, ss = 0.f;
    #pragma unroll
    for (int i = 0; i < 8; ++i) {
        const float4 e = *reinterpret_cast<const float4*>(
            &epi[row][t8 * 32 + i * 4]);
        const int2 rb = *reinterpret_cast<const int2*>(xr + i * 4);
        const float f0 = e.x + us2f((ushort_t)((unsigned)rb.x & 0xffffu));
        const float f1 = e.y + us2f((ushort_t)((unsigned)rb.x >> 16));
        const float f2 = e.z + us2f((ushort_t)((unsigned)rb.y & 0xffffu));
        const float f3 = e.w + us2f((ushort_t)((unsigned)rb.y >> 16));
        v[i * 4]     = f0; v[i * 4 + 1] = f1;
        v[i * 4 + 2] = f2; v[i * 4 + 3] = f3;
        s  += f0 + f1 + f2 + f3;
        ss += f0 * f0 + f1 * f1 + f2 * f2 + f3 * f3;
    }
    s += __shfl_xor(s, 1); ss += __shfl_xor(ss, 1);
    s += __shfl_xor(s, 2); ss += __shfl_xor(ss, 2);
    s += __shfl_xor(s, 4); ss += __shfl_xor(ss, 4);
    const float mean = s * (1.f / 256.f);
    const float var = ss * (1.f / 256.f) - mean * mean;
    const float rs = rsqrtf(var + 1e-5f);
    if (m < M) {
        #pragma unroll
        for (int i = 0; i < 8; ++i) {
            const float4 g4 = *reinterpret_cast<const float4*>(
                &g[t8 * 32 + i * 4]);
            const float4 b4 = *reinterpret_cast<const float4*>(
                &beta[t8 * 32 + i * 4]);
            float4 o4;
            o4.x = (v[i * 4]     - mean) * rs * g4.x + b4.x;
            o4.y = (v[i * 4 + 1] - mean) * rs * g4.y + b4.y;
            o4.z = (v[i * 4 + 2] - mean) * rs * g4.z + b4.z;
            o4.w = (v[i * 4 + 3] - mean) * rs * g4.w + b4.w;
            *reinterpret_cast<float4*>(
                &out[(size_t)m * 256 + t8 * 32 + i * 4]) = o4;
        }
    }
}

// ---------------------------------------------------------------------------
// MS-deformable attention v7 (unchanged — at structural gather limit).
// ---------------------------------------------------------------------------
__global__ __launch_bounds__(256) void msda_kernel_v7(
    const ushort_t* __restrict__ og,     // [M,480] bf16: offs 0..319, logits 320..479
    const float* __restrict__ refp,      // [M,10]
    const ushort_t* __restrict__ value,  // [M,256] bf16 = (B,L,H,32)
    bf16* __restrict__ out,              // [M,256] bf16
    int M, int L)
{
    const int tid = threadIdx.x;
    const int nb = gridDim.x;
    int wk = blockIdx.x;
    if ((nb & 7) == 0) {                       // bijective XCD remap
        const int per = nb >> 3;
        wk = (blockIdx.x & 7) * per + (blockIdx.x >> 3);
    }
    const int qbase = wk * 8;

    __shared__ float s_attn[8][160];   // 5120 B
    __shared__ int2  s_off[1280];      // 10240 B
    __shared__ int2  s_wh[1280];       // 10240 B -> total 25600 B

    for (int i = tid; i < 1280; i += 256) {
        int q = i / 160, j = i - q * 160;
        int qq = qbase + q;
        s_attn[q][j] = (qq < M) ? us2f(og[(size_t)qq * 480 + 320 + j]) : 0.f;
    }
    __syncthreads();

    if (tid < 64) {
        float* a = &s_attn[tid >> 3][(tid & 7) * 20];
        float mx = -1e30f;
        #pragma unroll
        for (int i = 0; i < 20; ++i) mx = fmaxf(mx, a[i]);
        float ssum = 0.f;
        #pragma unroll
        for (int i = 0; i < 20; ++i) {
            float e = __expf(a[i] - mx);
            a[i] = e;
            ssum += e;
        }
        float inv = 1.f / ssum;
        #pragma unroll
        for (int i = 0; i < 20; ++i) a[i] *= inv;
    }
    __syncthreads();

    #pragma unroll
    for (int it = 0; it < 5; ++it) {
        const int t = tid + it * 256;
        const int q  = t / 160;
        const int r  = t - q * 160;
        const int l  = (r - (r / 20) * 20) >> 2;
        const int qq = qbase + q;

        int2 offp = {0, 0};
        __half2 h01 = __floats2half2_rn(0.f, 0.f);
        __half2 h23 = h01;
        if (qq < M) {
            const int Wi = (l == 0) ? 100 : (l == 1) ? 50 : (l == 2) ? 25
                         : (l == 3) ? 13 : 7;
            const int s0 = (l == 0) ? 0 : (l == 1) ? 10000 : (l == 2) ? 12500
                         : (l == 3) ? 13125 : 13294;
            const float Wf = (float)Wi;
            const float ox = us2f(og[(size_t)qq * 480 + r * 2]);
            const float oy = us2f(og[(size_t)qq * 480 + r * 2 + 1]);
            const float2 rf = *reinterpret_cast<const float2*>(
                &refp[(size_t)qq * 10 + l * 2]);
            const float a = s_attn[q][r];

            const float px = fmaf(rf.x, Wf, -0.5f) + ox;
            const float py = fmaf(rf.y, Wf, -0.5f) + oy;
            const float x0f = floorf(px);
            const float y0f = floorf(py);
            const float lx = px - x0f;
            const float ly = py - y0f;
            const int x0 = (int)x0f;
            const int y0 = (int)y0f;

            const float wx0v = (x0 >= 0 && x0 < Wi) ? (1.f - lx) : 0.f;
            const float wx1v = (x0 + 1 >= 0 && x0 + 1 < Wi) ? lx : 0.f;
            const float wy0v = (y0 >= 0 && y0 < Wi) ? (1.f - ly) : 0.f;
            const float wy1v = (y0 + 1 >= 0 && y0 + 1 < Wi) ? ly : 0.f;

            const int c0 = min(max(x0, 0), Wi - 2);
            const int r0 = min(max(y0, 0), Wi - 2);
            const float swx0 = (x0 == c0 ? wx0v : 0.f) + (x0 + 1 == c0 ? wx1v : 0.f);
            const float swx1 = (x0 == c0 + 1 ? wx0v : 0.f) + (x0 + 1 == c0 + 1 ? wx1v : 0.f);
            const float swy0 = (y0 == r0 ? wy0v : 0.f) + (y0 + 1 == r0 ? wy1v : 0.f);
            const float swy1 = (y0 == r0 + 1 ? wy0v : 0.f) + (y0 + 1 == r0 + 1 ? wy1v : 0.f);

            offp.x = (s0 + r0 * Wi + c0) * 512;
            offp.y = offp.x + Wi * 512;
            h01 = __floats2half2_rn(a * swx0 * swy0, a * swx1 * swy0);
            h23 = __floats2half2_rn(a * swx0 * swy1, a * swx1 * swy1);
        }
        s_off[t] = offp;
        union { __half2 h; int i; } c0u, c1u;
        c0u.h = h01; c1u.h = h23;
        int2 wpk; wpk.x = c0u.i; wpk.y = c1u.i;
        s_wh[t] = wpk;
    }
    __syncthreads();

    const int qi  = tid >> 5;
    const int g   = tid & 31;
    const int h   = g >> 2;
    const int sub = g & 3;
    const int bq = qbase + qi;
    if (bq >= M) return;
    const int b = bq / L;

    const char* vb = (const char*)value + (size_t)b * L * 512 + h * 64 + sub * 16;

    float acc[8] = {};
    const int tb = qi * 160 + h * 20;
    #pragma unroll 2
    for (int p = 0; p < 20; ++p) {
        const int2 off = s_off[tb + p];
        const int2 whp = s_wh[tb + p];
        const int4 u00 = *reinterpret_cast<const int4*>(vb + off.x);
        const int4 u10 = *reinterpret_cast<const int4*>(vb + off.x + 512);
        const int4 u01 = *reinterpret_cast<const int4*>(vb + off.y);
        const int4 u11 = *reinterpret_cast<const int4*>(vb + off.y + 512);
        union { int i; __half2 h; } w0u, w1u;
        w0u.i = whp.x; w1u.i = whp.y;
        const float2 w01 = __half22float2(w0u.h);
        const float2 w23 = __half22float2(w1u.h);
        #define ACC4(u, wt)                                                        \
            acc[0] = fmaf(wt, __uint_as_float((unsigned)(u).x << 16), acc[0]);      \
            acc[1] = fmaf(wt, __uint_as_float((unsigned)(u).x & 0xffff0000u), acc[1]); \
            acc[2] = fmaf(wt, __uint_as_float((unsigned)(u).y << 16), acc[2]);      \
            acc[3] = fmaf(wt, __uint_as_float((unsigned)(u).y & 0xffff0000u), acc[3]); \
            acc[4] = fmaf(wt, __uint_as_float((unsigned)(u).z << 16), acc[4]);      \
            acc[5] = fmaf(wt, __uint_as_float((unsigned)(u).z & 0xffff0000u), acc[5]); \
            acc[6] = fmaf(wt, __uint_as_float((unsigned)(u).w << 16), acc[6]);      \
            acc[7] = fmaf(wt, __uint_as_float((unsigned)(u).w & 0xffff0000u), acc[7]);
        ACC4(u00, w01.x)
        ACC4(u10, w01.y)
        ACC4(u01, w23.x)
        ACC4(u11, w23.y)
        #undef ACC4
    }

    ushort_t o[8];
    #pragma unroll
    for (int i = 0; i < 8; ++i) o[i] = f2us(acc[i]);
    int4 pkt;
    pkt.x = (int)o[0] | ((int)o[1] << 16);
    pkt.y = (int)o[2] | ((int)o[3] << 16);
    pkt.z = (int)o[4] | ((int)o[5] << 16);
    pkt.w = (int)o[6] | ((int)o[7] << 16);
    *reinterpret_cast<int4*>((ushort_t*)out + (size_t)bq * 256 + h * 32 + sub * 8) = pkt;
}

// ---------------------------------------------------------------------------
extern "C" void kernel_launch(void* const* d_in, const int* in_sizes, int n_in,
                              void* d_out, int out_size, void* d_ws, size_t ws_size,
                              hipStream_t stream)
{
    const int B = 2, L = 13343, C = 256;
    const int M = B * L;  // 26686

    const float* src  = (const float*)d_in[0];
    const float* pos  = (const float*)d_in[1];
    const float* refp = (const float*)d_in[2];
    const float* wv   = (const float*)d_in[3];
    const float* bv   = (const float*)d_in[4];
    const float* wo   = (const float*)d_in[5];
    const float* bo   = (const float*)d_in[6];
    const float* wa   = (const float*)d_in[7];
    const float* ba   = (const float*)d_in[8];
    const float* wout = (const float*)d_in[9];
    const float* bout = (const float*)d_in[10];
    const float* ln1g = (const float*)d_in[11];
    const float* ln1b = (const float*)d_in[12];
    const float* w1   = (const float*)d_in[13];
    const float* b1   = (const float*)d_in[14];
    const float* w2   = (const float*)d_in[15];
    const float* b2   = (const float*)d_in[16];
    const float* ln2g = (const float*)d_in[17];
    const float* ln2b = (const float*)d_in[18];

    char* ws = (char*)d_ws;
    const size_t MB = 1ull << 20;
    // ---- workspace overlay ----
    bf16*  src_b  = (bf16*)(ws + 0);         // 13.7 MB
    bf16*  q_b    = (bf16*)(ws + 14 * MB);   // 13.7
    bf16*  val_b  = (bf16*)(ws + 28 * MB);   // 13.7
    bf16*  og     = (bf16*)(ws + 42 * MB);   // M*480 bf16 = 25.6 -> ends 67.6
    bf16*  acc_b  = (bf16*)(ws + 95 * MB);   // 13.7 -> ends 108.7
    bf16*  x_b    = (bf16*)(ws + 138 * MB);  // 13.7 (LN1 out, FFN input+resid)
    bf16* wvt    = (bf16*)(ws + 152 * MB);   // 256*256
    bf16* wcat   = wvt + 256 * 256;          // 480*256
    ushort_t* woutp = (ushort_t*)(wcat + 480 * 256); // packed wout, 256*256
    ushort_t* w1p = woutp + 256 * 256;               // packed, 2048*256
    ushort_t* w2p = w1p + 2048 * 256;                // packed, 256*2048
    float* bcat  = (float*)(w2p + 256 * 2048);       // 480 f32
    (void)ws_size; (void)n_in; (void)in_sizes; (void)out_size;

    const int mt64  = (M + 63) / 64;        // 417
    const int gm8   = (mt64 + 7) / 8;       // 53
    const int mt128 = (M + 127) / 128;      // 209
    const int gb8   = (mt128 + 7) / 8;      // 27
    const int mt32  = (M + 31) / 32;        // 834

    // ---- fused weight prep (one launch; wout/w1/w2 packed fragment-major) ----
    prep_kernel<<<1274, 256, 0, stream>>>(wv, wo, wa, wout, w1, w2, bo, ba,
                                          wvt, wcat, woutp, w1p, w2p, bcat);

    // ---- fused activation casts (float4) ----
    cast2_kernel<<<(M * C / 4 + 255) / 256, 256, 0, stream>>>(
        src, pos, src_b, q_b, M * C);

    // value = src @ wv + bv  (bf16)  [small kernel, NT=2]
    gemm_mfma_s<false, true, false, false, 2, 4><<<gm8 * 16, 256, 0, stream>>>(
        (const ushort_t*)src_b, (const ushort_t*)wvt, bv, nullptr, val_b,
        M, 256, 256, mt64);

    // og = q @ [wo|wa] + [bo|ba]  (bf16, N=480)  [BIG kernel, NT=4]
    gemm_mfma_b<false, true, false, false, 4><<<gb8 * 32, 256, 0, stream>>>(
        (const ushort_t*)q_b, (const ushort_t*)wcat, bcat, nullptr, og,
        M, 480, 256, mt128);

    // deformable attention -> acc_b (bf16)  [batch->XCD remap]
    msda_kernel_v7<<<(M + 7) / 8, 256, 0, stream>>>(
        (const ushort_t*)og, refp, (const ushort_t*)val_b, acc_b, M, L);

    // x_b = LN1( acc @ wout + bout + src )  — FUSED (y never hits HBM)
    woutln_kernel<<<mt32, 256, 0, stream>>>(
        (const ushort_t*)acc_b, woutp, bout, src, ln1g, ln1b, x_b, M);

    // out = LN2( x + relu(x@w1+b1)@w2 + b2 )  — FUSED v2 (R9 best, 112 µs)
    ffn_fused2<<<mt32, 256, 0, stream>>>(
        (const ushort_t*)x_b, w1p, w2p, b1, b2, ln2g, ln2b,
        (float*)d_out, M);
}

// Round 13
// 333.312 us; speedup vs baseline: 1.3982x; 1.0665x over previous
//
#include <hip/hip_runtime.h>
#include <hip/hip_bf16.h>
#include <hip/hip_fp16.h>

typedef __hip_bfloat16 bf16;
typedef unsigned short ushort_t;
typedef __attribute__((ext_vector_type(8))) short bf16x8;
typedef __attribute__((ext_vector_type(16))) float f32x16;

__device__ __forceinline__ float us2f(unsigned short u) {
    unsigned int x = ((unsigned int)u) << 16;
    return __uint_as_float(x);
}
__device__ __forceinline__ ushort_t f2us(float f) {
    return ((__hip_bfloat16_raw)__float2bfloat16(f)).x;
}

// async global->LDS, 16 B per lane. LDS dest = wave-uniform base + lane*16.
__device__ __forceinline__ void gl_lds16(const ushort_t* g, ushort_t* l) {
    __builtin_amdgcn_global_load_lds(
        (const __attribute__((address_space(1))) void*)g,
        (__attribute__((address_space(3))) void*)l, 16, 0, 0);
}

// ---------------------------------------------------------------------------
// Fused input cast (float4): src_b = bf16(src), q_b = bf16(src + pos)
// ---------------------------------------------------------------------------
__global__ __launch_bounds__(256) void cast2_kernel(
    const float* __restrict__ src, const float* __restrict__ pos,
    bf16* __restrict__ src_b, bf16* __restrict__ q_b, int n)
{
    int i = (blockIdx.x * 256 + threadIdx.x) * 4;
    if (i < n) {
        const float4 s4 = *reinterpret_cast<const float4*>(&src[i]);
        const float4 p4 = *reinterpret_cast<const float4*>(&pos[i]);
        int2 sp, qp;
        sp.x = (unsigned)f2us(s4.x) | ((unsigned)f2us(s4.y) << 16);
        sp.y = (unsigned)f2us(s4.z) | ((unsigned)f2us(s4.w) << 16);
        qp.x = (unsigned)f2us(s4.x + p4.x) | ((unsigned)f2us(s4.y + p4.y) << 16);
        qp.y = (unsigned)f2us(s4.z + p4.z) | ((unsigned)f2us(s4.w + p4.w) << 16);
        *reinterpret_cast<int2*>((ushort_t*)src_b + i) = sp;
        *reinterpret_cast<int2*>((ushort_t*)q_b + i) = qp;
    }
}

// ---------------------------------------------------------------------------
// Fused weight prep. Small weights (wv, wo|wa): transpose-cast to [N][K] bf16.
// wout/w1/w2: packed FRAGMENT-MAJOR:
//   mode-1 fragment (ng,t,kw,lane): 16 B = W[k=t*32+kw*16+(l>>5)*8+e][n=ng*32+(l&31)]
//        at ushort ((ng*8+t)*2+kw)*512 + lane*8   (wout: ng 0..7; w1: ng 0..63)
//   w2p  fragment (c,nq,t,kw,lane): w2[f=c*128+t*32+kw*16+(l>>5)*8+e][n=nq*32+(l&31)]
//        at ushort (((c*8+nq)*4+t)*2+kw)*512 + lane*8
// ---------------------------------------------------------------------------
__global__ __launch_bounds__(256) void prep_kernel(
    const float* __restrict__ wv, const float* __restrict__ wo,
    const float* __restrict__ wa, const float* __restrict__ wout,
    const float* __restrict__ w1, const float* __restrict__ w2,
    const float* __restrict__ bo, const float* __restrict__ ba,
    bf16* __restrict__ wvt, bf16* __restrict__ wcat,
    ushort_t* __restrict__ woutp,
    ushort_t* __restrict__ w1p, ushort_t* __restrict__ w2p,
    float* __restrict__ bcat)
{
    __shared__ float tile[32][33];
    const int b = blockIdx.x;
    const float* W; bf16* Wt = nullptr; ushort_t* Wp = nullptr;
    int K, N, tb, mode = 0;
    if (b < 64)        { W = wv;   Wt = wvt;            K = 256;  N = 256;  tb = b; }
    else if (b < 144)  { W = wo;   Wt = wcat;           K = 256;  N = 320;  tb = b - 64; }
    else if (b < 184)  { W = wa;   Wt = wcat + 320*256; K = 256;  N = 160;  tb = b - 144; }
    else if (b < 248)  { W = wout; Wp = woutp; mode = 1; K = 256; N = 256;  tb = b - 184; }
    else if (b < 760)  { W = w1;   Wp = w1p; mode = 1;  K = 256;  N = 2048; tb = b - 248; }
    else if (b < 1272) { W = w2;   Wp = w2p; mode = 2;  K = 2048; N = 256;  tb = b - 760; }
    else {
        int i = (b - 1272) * 256 + threadIdx.x;
        if (i < 320) bcat[i] = bo[i];
        else if (i < 480) bcat[i] = ba[i - 320];
        return;
    }
    const int ntn = N >> 5;
    const int nb = (tb % ntn) * 32, kb = (tb / ntn) * 32;
    const int tx = threadIdx.x & 31, ty = threadIdx.x >> 5;  // 32 x 8
    #pragma unroll
    for (int i = 0; i < 32; i += 8) {
        int k = kb + ty + i, n = nb + tx;
        tile[ty + i][tx] = (k < K && n < N) ? W[(size_t)k * N + n] : 0.f;
    }
    __syncthreads();
    if (mode == 0) {
        #pragma unroll
        for (int i = 0; i < 32; i += 8) {
            int n = nb + ty + i, k = kb + tx;
            if (n < N && k < K)
                Wt[(size_t)n * K + k] = __float2bfloat16(tile[tx][ty + i]);
        }
    } else if (threadIdx.x < 128) {
        const int l = threadIdx.x & 63, kw = threadIdx.x >> 6;
        const int kb8 = kw * 16 + (l >> 5) * 8;
        const int nx = l & 31;
        ushort_t tmp[8];
        #pragma unroll
        for (int e = 0; e < 8; ++e) tmp[e] = f2us(tile[kb8 + e][nx]);
        size_t base;
        if (mode == 1)
            base = ((size_t)(((nb >> 5) * 8 + (kb >> 5)) * 2 + kw)) * 512;
        else
            base = ((size_t)((((kb >> 7) * 8 + (nb >> 5)) * 4 + ((kb >> 5) & 3)) * 2 + kw)) * 512;
        *reinterpret_cast<int4*>(Wp + base + l * 8) =
            *reinterpret_cast<const int4*>(tmp);
    }
}

// ---------------------------------------------------------------------------
// MFMA bf16 GEMM (64x128 tile, M-split), swizzled-LDS, double-buffered.
// (proven R5/R6 kernel — used for the value GEMM)
// ---------------------------------------------------------------------------
template<bool RELU, bool OUT_BF16, bool HAS_RESID, bool RESID_BF16, int NT, int WPE>
__global__ __launch_bounds__(256, WPE) void gemm_mfma_s(
    const ushort_t* __restrict__ A,    // [M][K] bf16
    const ushort_t* __restrict__ Bt,   // [N][K] bf16
    const float* __restrict__ bias,    // [N] f32
    const void* __restrict__ residv,   // [M][N] f32 or bf16
    void* __restrict__ outv, int M, int N, int K, int mtiles)
{
    __shared__ __align__(16) char smemraw[24576];
    ushort_t* Asmem = (ushort_t*)smemraw;
    ushort_t* Bsmem = (ushort_t*)(smemraw + 4096);
    float (*epi)[68] = (float(*)[68])smemraw;

    const int lid = blockIdx.x;
    const int tbk = lid >> 3;
    const int xb = tbk & (NT - 1);
    const int yg = (tbk / NT) * 8 + (lid & 7);
    if (yg >= mtiles) return;
    const int m0 = yg * 64;
    const int n0 = xb * 128;

    const int tid = threadIdx.x;
    const int lane = tid & 63;
    const int wave = tid >> 6;
    const int l32 = lane & 31;
    const int hi  = lane >> 5;
    const int wm = wave >> 1;
    const int wn = wave & 1;

    const int lsup = lane >> 3;
    const int clin = lane & 7;

    const int gsA = wave * 8 + lsup;
    const int csA = clin ^ (gsA & 7);
    int rA = m0 + gsA * 2 + (csA >> 2); if (rA > M - 1) rA = M - 1;
    const ushort_t* aP = A + (size_t)rA * K + (csA & 3) * 8;
    ushort_t* aL = Asmem + wave * 512;

    const ushort_t* bP[2]; ushort_t* bL[2];
    #pragma unroll
    for (int i = 0; i < 2; ++i) {
        const int gsB = wave * 16 + i * 8 + lsup;
        const int csB = clin ^ (gsB & 7);
        int rB = n0 + gsB * 2 + (csB >> 2); if (rB > N - 1) rB = N - 1;
        bP[i] = Bt + (size_t)rB * K + (csB & 3) * 8;
        bL[i] = Bsmem + (wave * 16 + i * 8) * 64;
    }

    const int arow = wm * 32 + l32;
    const int asup = arow >> 1;
    const ushort_t* aR[2];
    #pragma unroll
    for (int kw = 0; kw < 2; ++kw) {
        const int q = kw * 2 + hi;
        const int slot = (((arow & 1) << 2) | q) ^ (asup & 7);
        aR[kw] = Asmem + asup * 64 + slot * 8;
    }
    const ushort_t* bR[2][2];
    #pragma unroll
    for (int j = 0; j < 2; ++j) {
        const int brow = wn * 64 + j * 32 + l32;
        const int bsup = brow >> 1;
        #pragma unroll
        for (int kw = 0; kw < 2; ++kw) {
            const int q = kw * 2 + hi;
            const int slot = (((brow & 1) << 2) | q) ^ (bsup & 7);
            bR[j][kw] = Bsmem + bsup * 64 + slot * 8;
        }
    }

    f32x16 acc[2] = {};

    auto stage = [&](int ofs) {
        gl_lds16(aP, aL + ofs);             aP    += 32;
        gl_lds16(bP[0], bL[0] + ofs);       bP[0] += 32;
        gl_lds16(bP[1], bL[1] + ofs);       bP[1] += 32;
    };
    auto compute = [&](int ofs) {
        #pragma unroll
        for (int kw = 0; kw < 2; ++kw) {
            const bf16x8 af = *reinterpret_cast<const bf16x8*>(aR[kw] + ofs);
            #pragma unroll
            for (int j = 0; j < 2; ++j)
                acc[j] = __builtin_amdgcn_mfma_f32_32x32x16_bf16(
                    af, *reinterpret_cast<const bf16x8*>(bR[j][kw] + ofs),
                    acc[j], 0, 0, 0);
        }
    };

    const int ntile = K >> 5;
    stage(0);
    for (int t = 0; t < ntile; t += 2) {
        __syncthreads();
        stage(6144);
        compute(0);
        __syncthreads();
        if (t + 2 < ntile) stage(0);
        compute(6144);
    }
    __syncthreads();

    #pragma unroll
    for (int half = 0; half < 2; ++half) {
        if (wn == half) {
            #pragma unroll
            for (int j = 0; j < 2; ++j) {
                const int coll = j * 32 + l32;
                const int n = n0 + half * 64 + coll;
                const float bv = (n < N) ? bias[n] : 0.f;
                #pragma unroll
                for (int r = 0; r < 16; ++r) {
                    const int row = wm * 32 + hi * 4 + (r & 3) + (r >> 2) * 8;
                    epi[row][coll] = acc[j][r] + bv;
                }
            }
        }
        __syncthreads();
        #pragma unroll
        for (int i = 0; i < 4; ++i) {
            const int idx = i * 256 + tid;
            const int row = idx >> 4;
            const int c4  = idx & 15;
            const int m = m0 + row;
            const int n = n0 + half * 64 + c4 * 4;
            if (m < M && n + 3 < N) {
                float4 v = *reinterpret_cast<const float4*>(&epi[row][c4 * 4]);
                if (HAS_RESID) {
                    if (RESID_BF16) {
                        const int2 rw = *reinterpret_cast<const int2*>(
                            (const ushort_t*)residv + (size_t)m * N + n);
                        v.x += us2f((ushort_t)((unsigned)rw.x & 0xffffu));
                        v.y += us2f((ushort_t)((unsigned)rw.x >> 16));
                        v.z += us2f((ushort_t)((unsigned)rw.y & 0xffffu));
                        v.w += us2f((ushort_t)((unsigned)rw.y >> 16));
                    } else {
                        const float4 r4 = *reinterpret_cast<const float4*>(
                            (const float*)residv + (size_t)m * N + n);
                        v.x += r4.x; v.y += r4.y; v.z += r4.z; v.w += r4.w;
                    }
                }
                if (RELU) {
                    v.x = fmaxf(v.x, 0.f); v.y = fmaxf(v.y, 0.f);
                    v.z = fmaxf(v.z, 0.f); v.w = fmaxf(v.w, 0.f);
                }
                if (OUT_BF16) {
                    int2 pk;
                    pk.x = (unsigned)f2us(v.x) | ((unsigned)f2us(v.y) << 16);
                    pk.y = (unsigned)f2us(v.z) | ((unsigned)f2us(v.w) << 16);
                    *reinterpret_cast<int2*>((ushort_t*)outv + (size_t)m * N + n) = pk;
                } else {
                    *reinterpret_cast<float4*>((float*)outv + (size_t)m * N + n) = v;
                }
            }
        }
        if (half == 0) __syncthreads();
    }
}

// ---------------------------------------------------------------------------
// BIG MFMA bf16 GEMM: 128x128 tile (proven R7 kernel — used for og, N=480).
// ---------------------------------------------------------------------------
template<bool RELU, bool OUT_BF16, bool HAS_RESID, bool RESID_BF16, int NT>
__global__ __launch_bounds__(256, 4) void gemm_mfma_b(
    const ushort_t* __restrict__ A,    // [M][K] bf16
    const ushort_t* __restrict__ Bt,   // [N][K] bf16
    const float* __restrict__ bias,    // [N] f32
    const void* __restrict__ residv,   // [M][N] f32 or bf16
    void* __restrict__ outv, int M, int N, int K, int mtiles)
{
    __shared__ __align__(16) char smemraw[32768];
    ushort_t* Asmem = (ushort_t*)smemraw;
    ushort_t* Bsmem = (ushort_t*)(smemraw + 8192);
    float (*epi)[68] = (float(*)[68])smemraw;

    const int lid = blockIdx.x;
    const int tbk = lid >> 3;
    const int xb = tbk & (NT - 1);
    const int yg = (tbk / NT) * 8 + (lid & 7);
    if (yg >= mtiles) return;
    const int m0 = yg * 128;
    const int n0 = xb * 128;

    const int tid = threadIdx.x;
    const int lane = tid & 63;
    const int wave = tid >> 6;
    const int l32 = lane & 31;
    const int hi  = lane >> 5;
    const int wm = wave >> 1;
    const int wn = wave & 1;

    const int lsup = lane >> 3;
    const int clin = lane & 7;
    const ushort_t *aP[2], *bP[2];
    ushort_t *aL[2], *bL[2];
    #pragma unroll
    for (int i = 0; i < 2; ++i) {
        const int gs = wave * 16 + i * 8 + lsup;
        const int cs = clin ^ (gs & 7);
        int rA = m0 + gs * 2 + (cs >> 2); if (rA > M - 1) rA = M - 1;
        aP[i] = A + (size_t)rA * K + (cs & 3) * 8;
        aL[i] = Asmem + (wave * 16 + i * 8) * 64;
        int rB = n0 + gs * 2 + (cs >> 2); if (rB > N - 1) rB = N - 1;
        bP[i] = Bt + (size_t)rB * K + (cs & 3) * 8;
        bL[i] = Bsmem + (wave * 16 + i * 8) * 64;
    }

    const ushort_t* aR[2][2];
    const ushort_t* bR[2][2];
    #pragma unroll
    for (int mi = 0; mi < 2; ++mi) {
        const int arow = wm * 64 + mi * 32 + l32;
        const int asup = arow >> 1;
        #pragma unroll
        for (int kw = 0; kw < 2; ++kw) {
            const int q = kw * 2 + hi;
            const int slot = (((arow & 1) << 2) | q) ^ (asup & 7);
            aR[mi][kw] = Asmem + asup * 64 + slot * 8;
        }
    }
    #pragma unroll
    for (int ni = 0; ni < 2; ++ni) {
        const int brow = wn * 64 + ni * 32 + l32;
        const int bsup = brow >> 1;
        #pragma unroll
        for (int kw = 0; kw < 2; ++kw) {
            const int q = kw * 2 + hi;
            const int slot = (((brow & 1) << 2) | q) ^ (bsup & 7);
            bR[ni][kw] = Bsmem + bsup * 64 + slot * 8;
        }
    }

    f32x16 a00 = {}, a01 = {}, a10 = {}, a11 = {};

    auto stage = [&](int ofs) {
        gl_lds16(aP[0], aL[0] + ofs); aP[0] += 32;
        gl_lds16(aP[1], aL[1] + ofs); aP[1] += 32;
        gl_lds16(bP[0], bL[0] + ofs); bP[0] += 32;
        gl_lds16(bP[1], bL[1] + ofs); bP[1] += 32;
    };
    auto compute = [&](int ofs) {
        #pragma unroll
        for (int kw = 0; kw < 2; ++kw) {
            const bf16x8 af0 = *reinterpret_cast<const bf16x8*>(aR[0][kw] + ofs);
            const bf16x8 af1 = *reinterpret_cast<const bf16x8*>(aR[1][kw] + ofs);
            const bf16x8 bf0 = *reinterpret_cast<const bf16x8*>(bR[0][kw] + ofs);
            const bf16x8 bf1 = *reinterpret_cast<const bf16x8*>(bR[1][kw] + ofs);
            a00 = __builtin_amdgcn_mfma_f32_32x32x16_bf16(af0, bf0, a00, 0, 0, 0);
            a01 = __builtin_amdgcn_mfma_f32_32x32x16_bf16(af0, bf1, a01, 0, 0, 0);
            a10 = __builtin_amdgcn_mfma_f32_32x32x16_bf16(af1, bf0, a10, 0, 0, 0);
            a11 = __builtin_amdgcn_mfma_f32_32x32x16_bf16(af1, bf1, a11, 0, 0, 0);
        }
    };

    const int ntile = K >> 5;
    stage(0);
    for (int t = 0; t < ntile; t += 2) {
        __syncthreads();
        stage(8192);
        compute(0);
        __syncthreads();
        if (t + 2 < ntile) stage(0);
        compute(8192);
    }
    __syncthreads();

    #pragma unroll
    for (int qd = 0; qd < 4; ++qd) {
        const int rh = qd >> 1, ch = qd & 1;
        if (qd) __syncthreads();
        if (wm == rh && wn == ch) {
            #pragma unroll
            for (int ni = 0; ni < 2; ++ni) {
                const int col = ni * 32 + l32;
                const int n = n0 + ch * 64 + col;
                const float bv = (n < N) ? bias[n] : 0.f;
                #pragma unroll
                for (int mi = 0; mi < 2; ++mi) {
                    const f32x16& ac = (mi == 0) ? (ni == 0 ? a00 : a01)
                                                 : (ni == 0 ? a10 : a11);
                    #pragma unroll
                    for (int r = 0; r < 16; ++r) {
                        const int row = mi * 32 + hi * 4 + (r & 3) + (r >> 2) * 8;
                        epi[row][col] = ac[r] + bv;
                    }
                }
            }
        }
        __syncthreads();
        #pragma unroll
        for (int i = 0; i < 4; ++i) {
            const int idx = i * 256 + tid;
            const int row = idx >> 4;
            const int c4  = idx & 15;
            const int m = m0 + rh * 64 + row;
            const int n = n0 + ch * 64 + c4 * 4;
            if (m < M && n + 3 < N) {
                float4 v = *reinterpret_cast<const float4*>(&epi[row][c4 * 4]);
                if (HAS_RESID) {
                    if (RESID_BF16) {
                        const int2 rw = *reinterpret_cast<const int2*>(
                            (const ushort_t*)residv + (size_t)m * N + n);
                        v.x += us2f((ushort_t)((unsigned)rw.x & 0xffffu));
                        v.y += us2f((ushort_t)((unsigned)rw.x >> 16));
                        v.z += us2f((ushort_t)((unsigned)rw.y & 0xffffu));
                        v.w += us2f((ushort_t)((unsigned)rw.y >> 16));
                    } else {
                        const float4 r4 = *reinterpret_cast<const float4*>(
                            (const float*)residv + (size_t)m * N + n);
                        v.x += r4.x; v.y += r4.y; v.z += r4.z; v.w += r4.w;
                    }
                }
                if (RELU) {
                    v.x = fmaxf(v.x, 0.f); v.y = fmaxf(v.y, 0.f);
                    v.z = fmaxf(v.z, 0.f); v.w = fmaxf(v.w, 0.f);
                }
                if (OUT_BF16) {
                    int2 pk;
                    pk.x = (unsigned)f2us(v.x) | ((unsigned)f2us(v.y) << 16);
                    pk.y = (unsigned)f2us(v.z) | ((unsigned)f2us(v.w) << 16);
                    *reinterpret_cast<int2*>((ushort_t*)outv + (size_t)m * N + n) = pk;
                } else {
                    *reinterpret_cast<float4*>((float*)outv + (size_t)m * N + n) = v;
                }
            }
        }
    }
}

// ---------------------------------------------------------------------------
// FUSED wout-GEMM + LN1 (R12-verified): x_b = LN1( acc @ wout + bout + src ).
// ---------------------------------------------------------------------------
__global__ __launch_bounds__(256, 4) void woutln_kernel(
    const ushort_t* __restrict__ A,    // acc_b [M][256] bf16
    const ushort_t* __restrict__ Wp,   // packed wout, 128 KB
    const float* __restrict__ bias,    // bout
    const float* __restrict__ resid,   // src f32 [M][256]
    const float* __restrict__ g, const float* __restrict__ beta,
    bf16* __restrict__ out, int M)     // x_b
{
    __shared__ __align__(16) char smem[33280];
    ushort_t* Xs = (ushort_t*)smem;
    float (*epi)[260] = (float(*)[260])smem;

    const int m0 = blockIdx.x * 32;
    const int tid = threadIdx.x;
    const int lane = tid & 63;
    const int wave = tid >> 6;
    const int l32 = lane & 31;
    const int hi  = lane >> 5;

    {
        const int lsup = (wave & 1) * 8 + (lane >> 3);
        const int clin = lane & 7;
        const int cs = clin ^ (lsup & 7);
        int r = m0 + lsup * 2 + (cs >> 2); if (r > M - 1) r = M - 1;
        const ushort_t* xp = A + (size_t)r * 256 + (cs & 3) * 8;
        ushort_t* xl = Xs + (wave & 1) * 512;
        #pragma unroll
        for (int p = 0; p < 4; ++p) {
            const int t = p * 2 + (wave >> 1);
            gl_lds16(xp + t * 32, xl + t * 1024);
        }
    }

    int aOff[2];
    {
        const int sr = l32 >> 1;
        #pragma unroll
        for (int kw = 0; kw < 2; ++kw) {
            const int q = kw * 2 + hi;
            const int slot = (((l32 & 1) << 2) | q) ^ (sr & 7);
            aOff[kw] = sr * 64 + slot * 8;
        }
    }

    f32x16 za0 = {}, za1 = {};
    __syncthreads();

    const int nq0 = wave * 2;
    #pragma unroll
    for (int t = 0; t < 8; ++t) {
        #pragma unroll
        for (int kw = 0; kw < 2; ++kw) {
            const bf16x8 af = *reinterpret_cast<const bf16x8*>(
                Xs + t * 1024 + aOff[kw]);
            const bf16x8 b0 = *reinterpret_cast<const bf16x8*>(
                Wp + ((nq0 * 8 + t) * 2 + kw) * 512 + lane * 8);
            const bf16x8 b1 = *reinterpret_cast<const bf16x8*>(
                Wp + (((nq0 + 1) * 8 + t) * 2 + kw) * 512 + lane * 8);
            za0 = __builtin_amdgcn_mfma_f32_32x32x16_bf16(af, b0, za0, 0, 0, 0);
            za1 = __builtin_amdgcn_mfma_f32_32x32x16_bf16(af, b1, za1, 0, 0, 0);
        }
    }

    __syncthreads();

    #pragma unroll
    for (int j = 0; j < 2; ++j) {
        const int col = wave * 64 + j * 32 + l32;
        const float bz = bias[col];
        const f32x16& zz = j ? za1 : za0;
        #pragma unroll
        for (int r = 0; r < 16; ++r)
            epi[(r & 3) + 8 * (r >> 2) + 4 * hi][col] = zz[r] + bz;
    }
    __syncthreads();

    const int row = tid >> 3, t8 = tid & 7;
    const int m = m0 + row;
    const int mc = (m < M) ? m : (M - 1);
    const float* xr = resid + (size_t)mc * 256 + t8 * 32;
    float v[32];
    float s = 0.f, ss = 0.f;
    #pragma unroll
    for (int i = 0; i < 8; ++i) {
        const float4 e = *reinterpret_cast<const float4*>(
            &epi[row][t8 * 32 + i * 4]);
        const float4 r4 = *reinterpret_cast<const float4*>(xr + i * 4);
        const float f0 = e.x + r4.x;
        const float f1 = e.y + r4.y;
        const float f2 = e.z + r4.z;
        const float f3 = e.w + r4.w;
        v[i * 4]     = f0; v[i * 4 + 1] = f1;
        v[i * 4 + 2] = f2; v[i * 4 + 3] = f3;
        s  += f0 + f1 + f2 + f3;
        ss += f0 * f0 + f1 * f1 + f2 * f2 + f3 * f3;
    }
    s += __shfl_xor(s, 1); ss += __shfl_xor(ss, 1);
    s += __shfl_xor(s, 2); ss += __shfl_xor(ss, 2);
    s += __shfl_xor(s, 4); ss += __shfl_xor(ss, 4);
    const float mean = s * (1.f / 256.f);
    const float var = ss * (1.f / 256.f) - mean * mean;
    const float rs = rsqrtf(var + 1e-5f);
    if (m < M) {
        #pragma unroll
        for (int i = 0; i < 8; ++i) {
            const float4 g4 = *reinterpret_cast<const float4*>(
                &g[t8 * 32 + i * 4]);
            const float4 b4 = *reinterpret_cast<const float4*>(
                &beta[t8 * 32 + i * 4]);
            float4 o4;
            o4.x = (v[i * 4]     - mean) * rs * g4.x + b4.x;
            o4.y = (v[i * 4 + 1] - mean) * rs * g4.y + b4.y;
            o4.z = (v[i * 4 + 2] - mean) * rs * g4.z + b4.z;
            o4.w = (v[i * 4 + 3] - mean) * rs * g4.w + b4.w;
            int2 pk;
            pk.x = (unsigned)f2us(o4.x) | ((unsigned)f2us(o4.y) << 16);
            pk.y = (unsigned)f2us(o4.z) | ((unsigned)f2us(o4.w) << 16);
            *reinterpret_cast<int2*>(
                (ushort_t*)out + (size_t)m * 256 + t8 * 32 + i * 4) = pk;
        }
    }
}

// ---------------------------------------------------------------------------
// FUSED FFN v5: 64-row blocks (417), packed coalesced weights loaded ONCE
// per chunk and fed to BOTH 32-row halves -> w1+w2 L2 traffic halves vs v2
// (1.67 GB -> 0.85 GB) and 2x MFMA between barriers. Inner loop = v2's
// verified structure duplicated per half with shared B-fragments.
// LDS 48 KB (Xs 32K @0, Hs 2x8K @32768); epi[32][260] overlay, 2-pass epi.
// za 4 + transient h 4 f32x16 -> ~190 VGPR -> (256,2).
// ---------------------------------------------------------------------------
__global__ __launch_bounds__(256, 2) void ffn_fused5(
    const ushort_t* __restrict__ X,    // [M][256] bf16 (post-LN1 x_b)
    const ushort_t* __restrict__ W1p,  // packed, 1 MB
    const ushort_t* __restrict__ W2p,  // packed, 1 MB
    const float* __restrict__ b1, const float* __restrict__ b2,
    const float* __restrict__ g, const float* __restrict__ beta,
    float* __restrict__ out, int M)
{
    __shared__ __align__(16) char smem[49152];
    ushort_t* Xs = (ushort_t*)smem;            // 2 halves x 8 k-tiles x 1024 us
    ushort_t* Hs = (ushort_t*)(smem + 32768);  // 2 halves x 4096 us = 16 KB
    float (*epi)[260] = (float(*)[260])smem;   // 32 x 260 f32 overlay

    const int m0 = blockIdx.x * 64;
    const int tid = threadIdx.x;
    const int lane = tid & 63;
    const int wave = tid >> 6;
    const int l32 = lane & 31;
    const int hi  = lane >> 5;

    // ---- stage X: both 32-row halves (proven pattern x2) ----
    #pragma unroll
    for (int hf = 0; hf < 2; ++hf) {
        const int lsup = (wave & 1) * 8 + (lane >> 3);
        const int clin = lane & 7;
        const int cs = clin ^ (lsup & 7);
        int r = m0 + hf * 32 + lsup * 2 + (cs >> 2); if (r > M - 1) r = M - 1;
        const ushort_t* xp = X + (size_t)r * 256 + (cs & 3) * 8;
        ushort_t* xl = Xs + hf * 8192 + (wave & 1) * 512;
        #pragma unroll
        for (int p = 0; p < 4; ++p) {
            const int t = p * 2 + (wave >> 1);
            gl_lds16(xp + t * 32, xl + t * 1024);
        }
    }

    int aOff[2];
    {
        const int sr = l32 >> 1;
        #pragma unroll
        for (int kw = 0; kw < 2; ++kw) {
            const int q = kw * 2 + hi;
            const int slot = (((l32 & 1) << 2) | q) ^ (sr & 7);
            aOff[kw] = sr * 64 + slot * 8;
        }
    }
    int hadr[16];
    #pragma unroll
    for (int r = 0; r < 16; ++r) {
        const int m = (r & 3) + 8 * (r >> 2) + 4 * hi;
        const int slot = (((m & 1) << 2) | (l32 >> 3)) ^ ((m >> 1) & 7);
        hadr[r] = wave * 1024 + (m >> 1) * 64 + slot * 8 + (l32 & 7);
    }

    f32x16 za00 = {}, za01 = {}, za10 = {}, za11 = {};
    __syncthreads();  // X staged (barrier drains vmcnt)

    for (int c = 0; c < 16; ++c) {
        // ---- stage 1: both halves, SHARED w1 fragments ----
        f32x16 h0a = {}, h1a = {}, h0b = {}, h1b = {};
        const int hcg = c * 4 + wave;
        const ushort_t* w1c = W1p + (size_t)hcg * 8192;
        #pragma unroll
        for (int t = 0; t < 8; t += 2) {
            #pragma unroll
            for (int kw = 0; kw < 2; ++kw) {
                const bf16x8 b0 = *reinterpret_cast<const bf16x8*>(
                    w1c + (t * 2 + kw) * 512 + lane * 8);
                const bf16x8 b1f = *reinterpret_cast<const bf16x8*>(
                    w1c + ((t + 1) * 2 + kw) * 512 + lane * 8);
                const bf16x8 a0a = *reinterpret_cast<const bf16x8*>(
                    Xs + t * 1024 + aOff[kw]);
                const bf16x8 a1a = *reinterpret_cast<const bf16x8*>(
                    Xs + (t + 1) * 1024 + aOff[kw]);
                const bf16x8 a0b = *reinterpret_cast<const bf16x8*>(
                    Xs + 8192 + t * 1024 + aOff[kw]);
                const bf16x8 a1b = *reinterpret_cast<const bf16x8*>(
                    Xs + 8192 + (t + 1) * 1024 + aOff[kw]);
                h0a = __builtin_amdgcn_mfma_f32_32x32x16_bf16(a0a, b0, h0a, 0, 0, 0);
                h1a = __builtin_amdgcn_mfma_f32_32x32x16_bf16(a1a, b1f, h1a, 0, 0, 0);
                h0b = __builtin_amdgcn_mfma_f32_32x32x16_bf16(a0b, b0, h0b, 0, 0, 0);
                h1b = __builtin_amdgcn_mfma_f32_32x32x16_bf16(a1b, b1f, h1b, 0, 0, 0);
            }
        }
        const float bb = b1[hcg * 32 + l32];

        __syncthreads();   // prior stage-2 readers of Hs done
        #pragma unroll
        for (int r = 0; r < 16; ++r) {
            Hs[hadr[r]]        = f2us(fmaxf(h0a[r] + h1a[r] + bb, 0.f));
            Hs[4096 + hadr[r]] = f2us(fmaxf(h0b[r] + h1b[r] + bb, 0.f));
        }
        __syncthreads();   // Hs ready

        // ---- stage 2: both halves, SHARED w2 fragments ----
        const ushort_t* w2c = W2p + (size_t)c * 32768;
        const int nq0 = wave * 2;
        #pragma unroll
        for (int t = 0; t < 4; ++t) {
            #pragma unroll
            for (int kw = 0; kw < 2; ++kw) {
                const bf16x8 bf0 = *reinterpret_cast<const bf16x8*>(
                    w2c + ((nq0 * 4 + t) * 2 + kw) * 512 + lane * 8);
                const bf16x8 bf1 = *reinterpret_cast<const bf16x8*>(
                    w2c + (((nq0 + 1) * 4 + t) * 2 + kw) * 512 + lane * 8);
                const bf16x8 afa = *reinterpret_cast<const bf16x8*>(
                    Hs + t * 1024 + aOff[kw]);
                const bf16x8 afb = *reinterpret_cast<const bf16x8*>(
                    Hs + 4096 + t * 1024 + aOff[kw]);
                za00 = __builtin_amdgcn_mfma_f32_32x32x16_bf16(afa, bf0, za00, 0, 0, 0);
                za01 = __builtin_amdgcn_mfma_f32_32x32x16_bf16(afa, bf1, za01, 0, 0, 0);
                za10 = __builtin_amdgcn_mfma_f32_32x32x16_bf16(afb, bf0, za10, 0, 0, 0);
                za11 = __builtin_amdgcn_mfma_f32_32x32x16_bf16(afb, bf1, za11, 0, 0, 0);
            }
        }
    }

    __syncthreads();  // compute done before epi overlay

    // ---- epilogue: 2 passes of 32 rows through epi[32][260] ----
    #pragma unroll
    for (int p = 0; p < 2; ++p) {
        if (p) __syncthreads();
        #pragma unroll
        for (int j = 0; j < 2; ++j) {
            const int col = wave * 64 + j * 32 + l32;
            const float bz = b2[col];
            const f32x16& zz = (p == 0) ? (j ? za01 : za00)
                                        : (j ? za11 : za10);
            #pragma unroll
            for (int r = 0; r < 16; ++r)
                epi[(r & 3) + 8 * (r >> 2) + 4 * hi][col] = zz[r] + bz;
        }
        __syncthreads();

        const int row = tid >> 3, t8 = tid & 7;
        const int m = m0 + p * 32 + row;
        const int mc = (m < M) ? m : (M - 1);
        const ushort_t* xr = X + (size_t)mc * 256 + t8 * 32;
        float v[32];
        float s = 0.f, ss = 0.f;
        #pragma unroll
        for (int i = 0; i < 8; ++i) {
            const float4 e = *reinterpret_cast<const float4*>(
                &epi[row][t8 * 32 + i * 4]);
            const int2 rb = *reinterpret_cast<const int2*>(xr + i * 4);
            const float f0 = e.x + us2f((ushort_t)((unsigned)rb.x & 0xffffu));
            const float f1 = e.y + us2f((ushort_t)((unsigned)rb.x >> 16));
            const float f2 = e.z + us2f((ushort_t)((unsigned)rb.y & 0xffffu));
            const float f3 = e.w + us2f((ushort_t)((unsigned)rb.y >> 16));
            v[i * 4]     = f0; v[i * 4 + 1] = f1;
            v[i * 4 + 2] = f2; v[i * 4 + 3] = f3;
            s  += f0 + f1 + f2 + f3;
            ss += f0 * f0 + f1 * f1 + f2 * f2 + f3 * f3;
        }
        s += __shfl_xor(s, 1); ss += __shfl_xor(ss, 1);
        s += __shfl_xor(s, 2); ss += __shfl_xor(ss, 2);
        s += __shfl_xor(s, 4); ss += __shfl_xor(ss, 4);
        const float mean = s * (1.f / 256.f);
        const float var = ss * (1.f / 256.f) - mean * mean;
        const float rs = rsqrtf(var + 1e-5f);
        if (m < M) {
            #pragma unroll
            for (int i = 0; i < 8; ++i) {
                const float4 g4 = *reinterpret_cast<const float4*>(
                    &g[t8 * 32 + i * 4]);
                const float4 b4 = *reinterpret_cast<const float4*>(
                    &beta[t8 * 32 + i * 4]);
                float4 o4;
                o4.x = (v[i * 4]     - mean) * rs * g4.x + b4.x;
                o4.y = (v[i * 4 + 1] - mean) * rs * g4.y + b4.y;
                o4.z = (v[i * 4 + 2] - mean) * rs * g4.z + b4.z;
                o4.w = (v[i * 4 + 3] - mean) * rs * g4.w + b4.w;
                *reinterpret_cast<float4*>(
                    &out[(size_t)m * 256 + t8 * 32 + i * 4]) = o4;
            }
        }
    }
}

// ---------------------------------------------------------------------------
// MS-deformable attention v7 (unchanged — at structural gather limit).
// ---------------------------------------------------------------------------
__global__ __launch_bounds__(256) void msda_kernel_v7(
    const ushort_t* __restrict__ og,     // [M,480] bf16: offs 0..319, logits 320..479
    const float* __restrict__ refp,      // [M,10]
    const ushort_t* __restrict__ value,  // [M,256] bf16 = (B,L,H,32)
    bf16* __restrict__ out,              // [M,256] bf16
    int M, int L)
{
    const int tid = threadIdx.x;
    const int nb = gridDim.x;
    int wk = blockIdx.x;
    if ((nb & 7) == 0) {                       // bijective XCD remap
        const int per = nb >> 3;
        wk = (blockIdx.x & 7) * per + (blockIdx.x >> 3);
    }
    const int qbase = wk * 8;

    __shared__ float s_attn[8][160];   // 5120 B
    __shared__ int2  s_off[1280];      // 10240 B
    __shared__ int2  s_wh[1280];       // 10240 B -> total 25600 B

    for (int i = tid; i < 1280; i += 256) {
        int q = i / 160, j = i - q * 160;
        int qq = qbase + q;
        s_attn[q][j] = (qq < M) ? us2f(og[(size_t)qq * 480 + 320 + j]) : 0.f;
    }
    __syncthreads();

    if (tid < 64) {
        float* a = &s_attn[tid >> 3][(tid & 7) * 20];
        float mx = -1e30f;
        #pragma unroll
        for (int i = 0; i < 20; ++i) mx = fmaxf(mx, a[i]);
        float ssum = 0.f;
        #pragma unroll
        for (int i = 0; i < 20; ++i) {
            float e = __expf(a[i] - mx);
            a[i] = e;
            ssum += e;
        }
        float inv = 1.f / ssum;
        #pragma unroll
        for (int i = 0; i < 20; ++i) a[i] *= inv;
    }
    __syncthreads();

    #pragma unroll
    for (int it = 0; it < 5; ++it) {
        const int t = tid + it * 256;
        const int q  = t / 160;
        const int r  = t - q * 160;
        const int l  = (r - (r / 20) * 20) >> 2;
        const int qq = qbase + q;

        int2 offp = {0, 0};
        __half2 h01 = __floats2half2_rn(0.f, 0.f);
        __half2 h23 = h01;
        if (qq < M) {
            const int Wi = (l == 0) ? 100 : (l == 1) ? 50 : (l == 2) ? 25
                         : (l == 3) ? 13 : 7;
            const int s0 = (l == 0) ? 0 : (l == 1) ? 10000 : (l == 2) ? 12500
                         : (l == 3) ? 13125 : 13294;
            const float Wf = (float)Wi;
            const float ox = us2f(og[(size_t)qq * 480 + r * 2]);
            const float oy = us2f(og[(size_t)qq * 480 + r * 2 + 1]);
            const float2 rf = *reinterpret_cast<const float2*>(
                &refp[(size_t)qq * 10 + l * 2]);
            const float a = s_attn[q][r];

            const float px = fmaf(rf.x, Wf, -0.5f) + ox;
            const float py = fmaf(rf.y, Wf, -0.5f) + oy;
            const float x0f = floorf(px);
            const float y0f = floorf(py);
            const float lx = px - x0f;
            const float ly = py - y0f;
            const int x0 = (int)x0f;
            const int y0 = (int)y0f;

            const float wx0v = (x0 >= 0 && x0 < Wi) ? (1.f - lx) : 0.f;
            const float wx1v = (x0 + 1 >= 0 && x0 + 1 < Wi) ? lx : 0.f;
            const float wy0v = (y0 >= 0 && y0 < Wi) ? (1.f - ly) : 0.f;
            const float wy1v = (y0 + 1 >= 0 && y0 + 1 < Wi) ? ly : 0.f;

            const int c0 = min(max(x0, 0), Wi - 2);
            const int r0 = min(max(y0, 0), Wi - 2);
            const float swx0 = (x0 == c0 ? wx0v : 0.f) + (x0 + 1 == c0 ? wx1v : 0.f);
            const float swx1 = (x0 == c0 + 1 ? wx0v : 0.f) + (x0 + 1 == c0 + 1 ? wx1v : 0.f);
            const float swy0 = (y0 == r0 ? wy0v : 0.f) + (y0 + 1 == r0 ? wy1v : 0.f);
            const float swy1 = (y0 == r0 + 1 ? wy0v : 0.f) + (y0 + 1 == r0 + 1 ? wy1v : 0.f);

            offp.x = (s0 + r0 * Wi + c0) * 512;
            offp.y = offp.x + Wi * 512;
            h01 = __floats2half2_rn(a * swx0 * swy0, a * swx1 * swy0);
            h23 = __floats2half2_rn(a * swx0 * swy1, a * swx1 * swy1);
        }
        s_off[t] = offp;
        union { __half2 h; int i; } c0u, c1u;
        c0u.h = h01; c1u.h = h23;
        int2 wpk; wpk.x = c0u.i; wpk.y = c1u.i;
        s_wh[t] = wpk;
    }
    __syncthreads();

    const int qi  = tid >> 5;
    const int g   = tid & 31;
    const int h   = g >> 2;
    const int sub = g & 3;
    const int bq = qbase + qi;
    if (bq >= M) return;
    const int b = bq / L;

    const char* vb = (const char*)value + (size_t)b * L * 512 + h * 64 + sub * 16;

    float acc[8] = {};
    const int tb = qi * 160 + h * 20;
    #pragma unroll 2
    for (int p = 0; p < 20; ++p) {
        const int2 off = s_off[tb + p];
        const int2 whp = s_wh[tb + p];
        const int4 u00 = *reinterpret_cast<const int4*>(vb + off.x);
        const int4 u10 = *reinterpret_cast<const int4*>(vb + off.x + 512);
        const int4 u01 = *reinterpret_cast<const int4*>(vb + off.y);
        const int4 u11 = *reinterpret_cast<const int4*>(vb + off.y + 512);
        union { int i; __half2 h; } w0u, w1u;
        w0u.i = whp.x; w1u.i = whp.y;
        const float2 w01 = __half22float2(w0u.h);
        const float2 w23 = __half22float2(w1u.h);
        #define ACC4(u, wt)                                                        \
            acc[0] = fmaf(wt, __uint_as_float((unsigned)(u).x << 16), acc[0]);      \
            acc[1] = fmaf(wt, __uint_as_float((unsigned)(u).x & 0xffff0000u), acc[1]); \
            acc[2] = fmaf(wt, __uint_as_float((unsigned)(u).y << 16), acc[2]);      \
            acc[3] = fmaf(wt, __uint_as_float((unsigned)(u).y & 0xffff0000u), acc[3]); \
            acc[4] = fmaf(wt, __uint_as_float((unsigned)(u).z << 16), acc[4]);      \
            acc[5] = fmaf(wt, __uint_as_float((unsigned)(u).z & 0xffff0000u), acc[5]); \
            acc[6] = fmaf(wt, __uint_as_float((unsigned)(u).w << 16), acc[6]);      \
            acc[7] = fmaf(wt, __uint_as_float((unsigned)(u).w & 0xffff0000u), acc[7]);
        ACC4(u00, w01.x)
        ACC4(u10, w01.y)
        ACC4(u01, w23.x)
        ACC4(u11, w23.y)
        #undef ACC4
    }

    ushort_t o[8];
    #pragma unroll
    for (int i = 0; i < 8; ++i) o[i] = f2us(acc[i]);
    int4 pkt;
    pkt.x = (int)o[0] | ((int)o[1] << 16);
    pkt.y = (int)o[2] | ((int)o[3] << 16);
    pkt.z = (int)o[4] | ((int)o[5] << 16);
    pkt.w = (int)o[6] | ((int)o[7] << 16);
    *reinterpret_cast<int4*>((ushort_t*)out + (size_t)bq * 256 + h * 32 + sub * 8) = pkt;
}

// ---------------------------------------------------------------------------
extern "C" void kernel_launch(void* const* d_in, const int* in_sizes, int n_in,
                              void* d_out, int out_size, void* d_ws, size_t ws_size,
                              hipStream_t stream)
{
    const int B = 2, L = 13343, C = 256;
    const int M = B * L;  // 26686

    const float* src  = (const float*)d_in[0];
    const float* pos  = (const float*)d_in[1];
    const float* refp = (const float*)d_in[2];
    const float* wv   = (const float*)d_in[3];
    const float* bv   = (const float*)d_in[4];
    const float* wo   = (const float*)d_in[5];
    const float* bo   = (const float*)d_in[6];
    const float* wa   = (const float*)d_in[7];
    const float* ba   = (const float*)d_in[8];
    const float* wout = (const float*)d_in[9];
    const float* bout = (const float*)d_in[10];
    const float* ln1g = (const float*)d_in[11];
    const float* ln1b = (const float*)d_in[12];
    const float* w1   = (const float*)d_in[13];
    const float* b1   = (const float*)d_in[14];
    const float* w2   = (const float*)d_in[15];
    const float* b2   = (const float*)d_in[16];
    const float* ln2g = (const float*)d_in[17];
    const float* ln2b = (const float*)d_in[18];

    char* ws = (char*)d_ws;
    const size_t MB = 1ull << 20;
    // ---- workspace overlay ----
    bf16*  src_b  = (bf16*)(ws + 0);         // 13.7 MB
    bf16*  q_b    = (bf16*)(ws + 14 * MB);   // 13.7
    bf16*  val_b  = (bf16*)(ws + 28 * MB);   // 13.7
    bf16*  og     = (bf16*)(ws + 42 * MB);   // M*480 bf16 = 25.6 -> ends 67.6
    bf16*  acc_b  = (bf16*)(ws + 95 * MB);   // 13.7 -> ends 108.7
    bf16*  x_b    = (bf16*)(ws + 138 * MB);  // 13.7 (LN1 out, FFN input+resid)
    bf16* wvt    = (bf16*)(ws + 152 * MB);   // 256*256
    bf16* wcat   = wvt + 256 * 256;          // 480*256
    ushort_t* woutp = (ushort_t*)(wcat + 480 * 256); // packed wout, 256*256
    ushort_t* w1p = woutp + 256 * 256;               // packed, 2048*256
    ushort_t* w2p = w1p + 2048 * 256;                // packed, 256*2048
    float* bcat  = (float*)(w2p + 256 * 2048);       // 480 f32
    (void)ws_size; (void)n_in; (void)in_sizes; (void)out_size;

    const int mt64  = (M + 63) / 64;        // 417
    const int gm8   = (mt64 + 7) / 8;       // 53
    const int mt128 = (M + 127) / 128;      // 209
    const int gb8   = (mt128 + 7) / 8;      // 27
    const int mt32  = (M + 31) / 32;        // 834

    // ---- fused weight prep (one launch; wout/w1/w2 packed fragment-major) ----
    prep_kernel<<<1274, 256, 0, stream>>>(wv, wo, wa, wout, w1, w2, bo, ba,
                                          wvt, wcat, woutp, w1p, w2p, bcat);

    // ---- fused activation casts (float4) ----
    cast2_kernel<<<(M * C / 4 + 255) / 256, 256, 0, stream>>>(
        src, pos, src_b, q_b, M * C);

    // value = src @ wv + bv  (bf16)  [small kernel, NT=2]
    gemm_mfma_s<false, true, false, false, 2, 4><<<gm8 * 16, 256, 0, stream>>>(
        (const ushort_t*)src_b, (const ushort_t*)wvt, bv, nullptr, val_b,
        M, 256, 256, mt64);

    // og = q @ [wo|wa] + [bo|ba]  (bf16, N=480)  [BIG kernel, NT=4]
    gemm_mfma_b<false, true, false, false, 4><<<gb8 * 32, 256, 0, stream>>>(
        (const ushort_t*)q_b, (const ushort_t*)wcat, bcat, nullptr, og,
        M, 480, 256, mt128);

    // deformable attention -> acc_b (bf16)  [batch->XCD remap]
    msda_kernel_v7<<<(M + 7) / 8, 256, 0, stream>>>(
        (const ushort_t*)og, refp, (const ushort_t*)val_b, acc_b, M, L);

    // x_b = LN1( acc @ wout + bout + src )  — FUSED (y never hits HBM)
    woutln_kernel<<<mt32, 256, 0, stream>>>(
        (const ushort_t*)acc_b, woutp, bout, src, ln1g, ln1b, x_b, M);

    // out = LN2( x + relu(x@w1+b1)@w2 + b2 )  — FUSED v5 (64-row, shared wgts)
    ffn_fused5<<<mt64, 256, 0, stream>>>(
        (const ushort_t*)x_b, w1p, w2p, b1, b2, ln2g, ln2b,
        (float*)d_out, M);
}